// Round 14
// baseline (254.472 us; speedup 1.0000x reference)
//
#include <hip/hip_runtime.h>
#include <cstdint>

typedef unsigned short u16;
typedef __attribute__((ext_vector_type(8))) short short8;
typedef __attribute__((ext_vector_type(4))) float floatx4;

#define BT    8192
#define TSEQ  2048
#define NBAT  4
#define CMOD  512
#define NH    4
#define HD    128
#define DFF   2048
#define CQKV  1536

__device__ __forceinline__ u16 f2bf(float f) {
  union { float f; uint32_t u; } v; v.f = f;
  uint32_t r = v.u + 0x7FFFu + ((v.u >> 16) & 1u);
  return (u16)(r >> 16);
}
__device__ __forceinline__ float bf2f(u16 u) {
  union { uint32_t u; float f; } v; v.u = ((uint32_t)u) << 16; return v.f;
}
__device__ __forceinline__ float exp2a(float x) {
  float r; asm("v_exp_f32 %0, %1" : "=v"(r) : "v"(x)); return r;
}
__device__ __forceinline__ float rcpa(float x) {
  float r; asm("v_rcp_f32 %0, %1" : "=v"(r) : "v"(x)); return r;
}

typedef __attribute__((address_space(1))) const unsigned int ga_u32;
typedef __attribute__((address_space(3))) unsigned int ls_u32;
__device__ __forceinline__ void glds16(const u16* g, u16* l) {
  __builtin_amdgcn_global_load_lds((ga_u32*)g, (ls_u32*)l, 16, 0, 0);
}

// ---------------- fused prep: 4 weight transposes + LN1 (frozen) ----------------
__device__ __forceinline__ void tcast_body(const float* __restrict__ W, u16* __restrict__ Wt,
                                           int K, int N, int bx, int by, int tid,
                                           float (*tile)[33]) {
  int n0 = bx * 32, k0 = by * 32;
  int tx = tid & 31, ty = tid >> 5;
  #pragma unroll
  for (int r = 0; r < 32; r += 8)
    tile[r + ty][tx] = W[(size_t)(k0 + r + ty) * N + n0 + tx];
  __syncthreads();
  #pragma unroll
  for (int r = 0; r < 32; r += 8)
    Wt[(size_t)(n0 + r + ty) * K + k0 + tx] = f2bf(tile[tx][r + ty]);
}

__global__ __launch_bounds__(256) void prep_kernel(
    const float* __restrict__ x, const float* __restrict__ g, const float* __restrict__ b,
    const float* __restrict__ wqkv, const float* __restrict__ wproj,
    const float* __restrict__ wff1, const float* __restrict__ wff2,
    u16* __restrict__ ln_out, u16* __restrict__ wqkvT, u16* __restrict__ wprojT,
    u16* __restrict__ wff1T, u16* __restrict__ wff2T) {
  __shared__ float tile[32][33];
  int bid = blockIdx.x, tid = threadIdx.x;
  if (bid < 768) {
    tcast_body(wqkv, wqkvT, CMOD, CQKV, bid % 48, bid / 48, tid, tile);
  } else if (bid < 1024) {
    int id = bid - 768; tcast_body(wproj, wprojT, CMOD, CMOD, id % 16, id / 16, tid, tile);
  } else if (bid < 2048) {
    int id = bid - 1024; tcast_body(wff1, wff1T, CMOD, DFF, id % 64, id / 64, tid, tile);
  } else if (bid < 3072) {
    int id = bid - 2048; tcast_body(wff2, wff2T, DFF, CMOD, id % 16, id / 16, tid, tile);
  } else {
    int row = (bid - 3072) * 4 + (tid >> 6);
    int lane = tid & 63;
    const float4* xr = (const float4*)(x + (size_t)row * CMOD);
    float4 a = xr[lane], c = xr[lane + 64];
    float s = a.x + a.y + a.z + a.w + c.x + c.y + c.z + c.w;
    float q = a.x*a.x + a.y*a.y + a.z*a.z + a.w*a.w
            + c.x*c.x + c.y*c.y + c.z*c.z + c.w*c.w;
    #pragma unroll
    for (int o = 32; o; o >>= 1) { s += __shfl_xor(s, o); q += __shfl_xor(q, o); }
    float mu = s * (1.0f / CMOD);
    float rstd = rsqrtf(q * (1.0f / CMOD) - mu * mu + 1e-5f);
    const float4* gr = (const float4*)g;
    const float4* br = (const float4*)b;
    float4 g0 = gr[lane], g1 = gr[lane + 64], b0 = br[lane], b1 = br[lane + 64];
    u16* orow = ln_out + (size_t)row * CMOD;
    int i0 = lane * 4, i1 = (lane + 64) * 4;
    orow[i0 + 0] = f2bf((a.x - mu) * rstd * g0.x + b0.x);
    orow[i0 + 1] = f2bf((a.y - mu) * rstd * g0.y + b0.y);
    orow[i0 + 2] = f2bf((a.z - mu) * rstd * g0.z + b0.z);
    orow[i0 + 3] = f2bf((a.w - mu) * rstd * g0.w + b0.w);
    orow[i1 + 0] = f2bf((c.x - mu) * rstd * g1.x + b1.x);
    orow[i1 + 1] = f2bf((c.y - mu) * rstd * g1.y + b1.y);
    orow[i1 + 2] = f2bf((c.z - mu) * rstd * g1.z + b1.z);
    orow[i1 + 3] = f2bf((c.w - mu) * rstd * g1.w + b1.w);
  }
}

// ---------------- layernorm (standalone, for LN2; frozen) ----------------
__global__ __launch_bounds__(256) void ln_kernel(const float* __restrict__ x,
                                                 const float* __restrict__ g,
                                                 const float* __restrict__ b,
                                                 u16* __restrict__ out) {
  int row = blockIdx.x * 4 + (threadIdx.x >> 6);
  int lane = threadIdx.x & 63;
  const float4* xr = (const float4*)(x + (size_t)row * CMOD);
  float4 a = xr[lane], c = xr[lane + 64];
  float s = a.x + a.y + a.z + a.w + c.x + c.y + c.z + c.w;
  float q = a.x*a.x + a.y*a.y + a.z*a.z + a.w*a.w
          + c.x*c.x + c.y*c.y + c.z*c.z + c.w*c.w;
  #pragma unroll
  for (int o = 32; o; o >>= 1) { s += __shfl_xor(s, o); q += __shfl_xor(q, o); }
  float mu = s * (1.0f / CMOD);
  float rstd = rsqrtf(q * (1.0f / CMOD) - mu * mu + 1e-5f);
  const float4* gr = (const float4*)g;
  const float4* br = (const float4*)b;
  float4 g0 = gr[lane], g1 = gr[lane + 64], b0 = br[lane], b1 = br[lane + 64];
  u16* orow = out + (size_t)row * CMOD;
  int i0 = lane * 4, i1 = (lane + 64) * 4;
  orow[i0 + 0] = f2bf((a.x - mu) * rstd * g0.x + b0.x);
  orow[i0 + 1] = f2bf((a.y - mu) * rstd * g0.y + b0.y);
  orow[i0 + 2] = f2bf((a.z - mu) * rstd * g0.z + b0.z);
  orow[i0 + 3] = f2bf((a.w - mu) * rstd * g0.w + b0.w);
  orow[i1 + 0] = f2bf((c.x - mu) * rstd * g1.x + b1.x);
  orow[i1 + 1] = f2bf((c.y - mu) * rstd * g1.y + b1.y);
  orow[i1 + 2] = f2bf((c.z - mu) * rstd * g1.z + b1.z);
  orow[i1 + 3] = f2bf((c.w - mu) * rstd * g1.w + b1.w);
}

// ---------------- MFMA GEMM: per-GEMM grid mapping (THE ONLY CHANGE) ----------------
// R13 A/B result: 1D XCD-swizzle (m-block in low bits) is a big win for fat-A,
// long-K GEMMs (FF2 45.5 -> <51.5-with-FF1-on-top, FETCH 140->~55MB) but REGRESSED
// short-K FF1 (<=44.8 -> 52us at near-ideal FETCH). Cherry-pick per kernel:
// SWZ=1 (proj, FF2): 1D grid, m0 = (bid & 63)*TM, n0 = (bid >> 6)*TN.
// SWZ=0 (QKV, FF1): R12's 2D grid. Math identical either way -> bit-identical.
template <int EPI, int TM, int TN, int MINW, int SWZ>
__global__ __launch_bounds__(256, MINW) void gemm_kernel(
    const u16* __restrict__ A, const u16* __restrict__ Bt, int K,
    const float* __restrict__ resid, float* __restrict__ outf,
    u16* __restrict__ ob0, u16* __restrict__ ob1, u16* __restrict__ ob2) {
  constexpr int MR  = TM / 32;
  constexpr int NR  = TN / 32;
  constexpr int NAR = TM / 64;
  constexpr int NBR = TN / 64;
  __shared__ __align__(16) u16 As[2][TM * 32];
  __shared__ __align__(16) u16 Bs[2][TN * 32];
  int tid = threadIdx.x;
  int lane = tid & 63, wave = tid >> 6;
  int lane16 = lane & 15, quad = lane >> 4;
  int m0, n0;
  if (SWZ) {
    int n1d = blockIdx.x;
    m0 = (n1d & 63) * TM;
    n0 = (n1d >> 6) * TN;
  } else {
    m0 = blockIdx.y * TM;
    n0 = blockIdx.x * TN;
  }
  int wm = (wave >> 1) * (TM / 2), wn = (wave & 1) * (TN / 2);

  floatx4 acc[MR][NR];
  #pragma unroll
  for (int i = 0; i < MR; i++)
    #pragma unroll
    for (int j = 0; j < NR; j++) acc[i][j] = (floatx4)(0.0f);

  const u16* agp[NAR]; u16* alp[NAR][2];
  const u16* bgp[NBR]; u16* blp[NBR][2];
  #pragma unroll
  for (int i = 0; i < NAR; i++) {
    int s = i * 256 + tid;
    agp[i] = A + (size_t)(m0 + (s >> 2)) * K + (s & 3) * 8;
    alp[i][0] = &As[0][(i * 256 + wave * 64) * 8];
    alp[i][1] = &As[1][(i * 256 + wave * 64) * 8];
  }
  #pragma unroll
  for (int i = 0; i < NBR; i++) {
    int s = i * 256 + tid;
    bgp[i] = Bt + (size_t)(n0 + (s >> 2)) * K + (s & 3) * 8;
    blp[i][0] = &Bs[0][(i * 256 + wave * 64) * 8];
    blp[i][1] = &Bs[1][(i * 256 + wave * 64) * 8];
  }

  int nk = K >> 5;
  #pragma unroll
  for (int i = 0; i < NAR; i++) glds16(agp[i], alp[i][0]);
  #pragma unroll
  for (int i = 0; i < NBR; i++) glds16(bgp[i], blp[i][0]);

  for (int kt = 0; kt < nk; kt++) {
    __syncthreads();
    int buf = kt & 1;
    if (kt + 1 < nk) {
      int k1 = (kt + 1) * 32;
      #pragma unroll
      for (int i = 0; i < NAR; i++) glds16(agp[i] + k1, alp[i][buf ^ 1]);
      #pragma unroll
      for (int i = 0; i < NBR; i++) glds16(bgp[i] + k1, blp[i][buf ^ 1]);
    }
    short8 af[MR];
    #pragma unroll
    for (int i = 0; i < MR; i++)
      af[i] = *(const short8*)&As[buf][(wm + i * 16 + lane16) * 32 + quad * 8];
    #pragma unroll
    for (int j = 0; j < NR; j++) {
      short8 bfj = *(const short8*)&Bs[buf][(wn + j * 16 + lane16) * 32 + quad * 8];
      #pragma unroll
      for (int i = 0; i < MR; i++)
        acc[i][j] = __builtin_amdgcn_mfma_f32_16x16x32_bf16(af[i], bfj, acc[i][j], 0, 0, 0);
    }
  }

  #pragma unroll
  for (int i = 0; i < MR; i++) {
    #pragma unroll
    for (int j = 0; j < NR; j++) {
      #pragma unroll
      for (int r = 0; r < 4; r++) {
        int m = m0 + wm + i * 16 + quad * 4 + r;
        int n = n0 + wn + j * 16 + lane16;
        float v = acc[i][j][r];
        if (EPI == 0) {
          int bb = m >> 11, t = m & 2047;
          int nn = n & 511, which = n >> 9;
          int h = nn >> 7, d = nn & 127;
          size_t base = (size_t)(bb * NH + h) * 262144;
          if (which == 0) {
            int t16 = t >> 4, l16 = t & 15, cc = d >> 5, qd = (d >> 3) & 3, e = d & 7;
            ob0[base + (size_t)((t16 * 16 + cc * 4 + qd) * 128 + l16 * 8 + e)] = f2bf(v * 0.12751743f);
          } else if (which == 1) {
            int kt = t >> 5, hf = (t >> 4) & 1, l16 = t & 15, cc = d >> 5, qd = (d >> 3) & 3, e = d & 7;
            ob1[base + (size_t)((kt * 8 + hf * 4 + cc) * 512 + qd * 128 + l16 * 8 + e)] = f2bf(v);
          } else {
            int kt = t >> 5, qv = (t >> 3) & 3, e = t & 7, j2 = d >> 4, l16 = d & 15;
            ob2[base + (size_t)((kt * 8 + j2) * 512 + qv * 128 + l16 * 8 + e)] = f2bf(v);
          }
        } else if (EPI == 1) {
          size_t idx = (size_t)m * CMOD + n;
          outf[idx] = v + resid[idx];
        } else if (EPI == 2) {
          float ge = 0.5f * v * (1.0f + erff(v * 0.70710678118654752f));
          ob0[(size_t)m * DFF + n] = f2bf(ge);
        } else {
          size_t idx = (size_t)m * CMOD + n;
          outf[idx] = v + resid[idx];
        }
      }
    }
  }
}

// ---------------- flash attention: R12 (frozen) ----------------
__global__ __launch_bounds__(128) void attn_kernel(const u16* __restrict__ qb,
                                                   const u16* __restrict__ kb,
                                                   const u16* __restrict__ vtb,
                                                   u16* __restrict__ po,
                                                   float* __restrict__ pl) {
  int tid = threadIdx.x, wave = tid >> 6, lane = tid & 63;
  int lane16 = lane & 15, quad = lane >> 4;
  int n1d = blockIdx.x;
  int bh = n1d & 15;
  int idx = 143 - (n1d >> 4);   // heavy (large qt) chunks dispatch first
  int g = 1;
  #pragma unroll
  for (int t = 2; t <= 8; t++) if (idx >= 2 * t * (t - 1)) g = t;
  int rem = idx - 2 * g * (g - 1);
  int qi = rem / g;
  int c  = rem - qi * g;
  int qt = ((g - 1) << 2) + qi;

  int q0w = qt * 64 + wave * 32;   // 32 rows per wave
  const u16* Qb = qb  + (size_t)bh * 262144;
  const u16* Kb = kb  + (size_t)bh * 262144;
  const u16* Vb = vtb + (size_t)bh * 262144;

  short8 aqA[4], aqB[4];
  {
    int t16 = q0w >> 4;
    #pragma unroll
    for (int cc = 0; cc < 4; cc++) {
      aqA[cc] = *(const short8*)&Qb[(size_t)((t16 * 16 + cc * 4 + quad) * 128 + lane16 * 8)];
      aqB[cc] = *(const short8*)&Qb[(size_t)(((t16 + 1) * 16 + cc * 4 + quad) * 128 + lane16 * 8)];
    }
  }

  int ktw   = (q0w >> 5) + 1;
  int ktblk = qt * 2 + 2;
  int kt0   = c * 8;
  int kend  = min(min(kt0 + 8, ktblk), ktw);

  floatx4 oA[8], oB[8];
  #pragma unroll
  for (int j = 0; j < 8; j++) { oA[j] = (floatx4)(0.0f); oB[j] = (floatx4)(0.0f); }
  floatx4 olA = (floatx4)(0.0f), olB = (floatx4)(0.0f);

  short8 ones;
  #pragma unroll
  for (int e = 0; e < 8; e++) ones[e] = (short)0x3F80;

  int addrA = (lane16 + ((quad & 1) << 5)) << 2;
  int addrB = addrA + 64;
  int q_gA = q0w + lane16;
  int q_gB = q0w + 16 + lane16;

#define ATTN_TAIL(S0, S1, O_, OL_, QG, KT)                                                          \
  {                                                                                                 \
    int k0b = (KT) * 32 + quad * 4;                                                                 \
    _Pragma("unroll")                                                                               \
    for (int r = 0; r < 4; r++) {                                                                   \
      float p0 = exp2a(S0[r]);                                                                      \
      float p1 = exp2a(S1[r]);                                                                      \
      if (k0b + r > (QG)) p0 = 0.0f;                                                                \
      if (k0b + r + 16 > (QG)) p1 = 0.0f;                                                           \
      S0[r] = p0; S1[r] = p1;                                                                       \
    }                                                                                               \
    uint32_t x0 = __builtin_amdgcn_perm(__float_as_uint(S0[1]), __float_as_uint(S0[0]), 0x07060302u); \
    uint32_t x1 = __builtin_amdgcn_perm(__float_as_uint(S0[3]), __float_as_uint(S0[2]), 0x07060302u); \
    uint32_t y0 = __builtin_amdgcn_perm(__float_as_uint(S1[1]), __float_as_uint(S1[0]), 0x07060302u); \
    uint32_t y1 = __builtin_amdgcn_perm(__float_as_uint(S1[3]), __float_as_uint(S1[2]), 0x07060302u); \
    int pAx0 = __builtin_amdgcn_ds_bpermute(addrA, (int)x0);                                        \
    int pAx1 = __builtin_amdgcn_ds_bpermute(addrA, (int)x1);                                        \
    int pBx0 = __builtin_amdgcn_ds_bpermute(addrB, (int)x0);                                        \
    int pBx1 = __builtin_amdgcn_ds_bpermute(addrB, (int)x1);                                        \
    int pAy0 = __builtin_amdgcn_ds_bpermute(addrA, (int)y0);                                        \
    int pAy1 = __builtin_amdgcn_ds_bpermute(addrA, (int)y1);                                        \
    int pBy0 = __builtin_amdgcn_ds_bpermute(addrB, (int)y0);                                        \
    int pBy1 = __builtin_amdgcn_ds_bpermute(addrB, (int)y1);                                        \
    union { uint32_t u[4]; short8 s; } pf;                                                          \
    bool hi = quad >= 2;                                                                            \
    pf.u[0] = (uint32_t)(hi ? pAy0 : pAx0);                                                         \
    pf.u[1] = (uint32_t)(hi ? pAy1 : pAx1);                                                         \
    pf.u[2] = (uint32_t)(hi ? pBy0 : pBx0);                                                         \
    pf.u[3] = (uint32_t)(hi ? pBy1 : pBx1);                                                         \
    _Pragma("unroll")                                                                               \
    for (int j = 0; j < 8; j++)                                                                     \
      O_[j] = __builtin_amdgcn_mfma_f32_16x16x32_bf16(pf.s, vfr[j], O_[j], 0, 0, 0);                \
    OL_ = __builtin_amdgcn_mfma_f32_16x16x32_bf16(pf.s, ones, OL_, 0, 0, 0);                        \
  }

  for (int kt = kt0; kt < kend; kt++) {
    const u16* kp = Kb + (size_t)kt * 4096 + lane * 8;
    const u16* vp = Vb + (size_t)kt * 4096 + lane * 8;
    short8 k0f[4], k1f[4];
    #pragma unroll
    for (int cc = 0; cc < 4; cc++) {
      k0f[cc] = *(const short8*)&kp[cc * 512];
      k1f[cc] = *(const short8*)&kp[(4 + cc) * 512];
    }

    floatx4 sA0 = (floatx4)(0.0f), sA1 = (floatx4)(0.0f);
    floatx4 sB0 = (floatx4)(0.0f), sB1 = (floatx4)(0.0f);
    #pragma unroll
    for (int cc = 0; cc < 4; cc++) {
      sA0 = __builtin_amdgcn_mfma_f32_16x16x32_bf16(k0f[cc], aqA[cc], sA0, 0, 0, 0);
      sA1 = __builtin_amdgcn_mfma_f32_16x16x32_bf16(k1f[cc], aqA[cc], sA1, 0, 0, 0);
      sB0 = __builtin_amdgcn_mfma_f32_16x16x32_bf16(k0f[cc], aqB[cc], sB0, 0, 0, 0);
      sB1 = __builtin_amdgcn_mfma_f32_16x16x32_bf16(k1f[cc], aqB[cc], sB1, 0, 0, 0);
    }

    short8 vfr[8];
    #pragma unroll
    for (int j = 0; j < 8; j++)
      vfr[j] = *(const short8*)&vp[j * 512];

    ATTN_TAIL(sA0, sA1, oA, olA, q_gA, kt);
    ATTN_TAIL(sB0, sB1, oB, olB, q_gB, kt);
  }
#undef ATTN_TAIL

  int slot = bh * 144 + 2 * g * (g - 1) + qi * g + c;
  u16* pob = po + (size_t)slot * 8192;
  #pragma unroll
  for (int r = 0; r < 4; r++) {
    int qrA = wave * 32 + quad * 4 + r;
    int qrB = qrA + 16;
    #pragma unroll
    for (int j = 0; j < 8; j++) {
      pob[qrA * 128 + j * 16 + lane16] = f2bf(oA[j][r]);
      pob[qrB * 128 + j * 16 + lane16] = f2bf(oB[j][r]);
    }
    if (lane16 == 0) {
      pl[slot * 64 + qrA] = olA[r];
      pl[slot * 64 + qrB] = olB[r];
    }
  }
}

// ---------------- reduce: R11 slot mapping (frozen) ----------------
__global__ __launch_bounds__(256) void reduce_kernel(const u16* __restrict__ po,
                                                     const float* __restrict__ pl,
                                                     u16* __restrict__ attn) {
  int bh = blockIdx.x >> 5, qt = blockIdx.x & 31;
  int tid = threadIdx.x;
  int g = (qt >> 2) + 1;
  int slot0 = bh * 144 + 2 * g * (g - 1) + (qt & 3) * g;
  int qrow = tid >> 2;
  int d0 = (tid & 3) * 32;
  float acc[32];
  #pragma unroll
  for (int i = 0; i < 32; i++) acc[i] = 0.0f;
  float l = 0.0f;
  for (int c = 0; c < g; c++) {
    int slot = slot0 + c;
    l += pl[slot * 64 + qrow];
    const short8* p = (const short8*)(po + (size_t)slot * 8192 + qrow * 128 + d0);
    #pragma unroll
    for (int v = 0; v < 4; v++) {
      short8 pk = p[v];
      #pragma unroll
      for (int e = 0; e < 8; e++) acc[v * 8 + e] += bf2f((u16)pk[e]);
    }
  }
  float inv = rcpa(l);
  int b = bh >> 2, h = bh & 3, t = qt * 64 + qrow;
  u16* orow = attn + ((size_t)(b * TSEQ + t)) * CMOD + h * HD + d0;
  #pragma unroll
  for (int v = 0; v < 4; v++) {
    short8 ov;
    #pragma unroll
    for (int e = 0; e < 8; e++) ov[e] = (short)f2bf(acc[v * 8 + e] * inv);
    *(short8*)(orow + v * 8) = ov;
  }
}

extern "C" void kernel_launch(void* const* d_in, const int* in_sizes, int n_in,
                              void* d_out, int out_size, void* d_ws, size_t ws_size,
                              hipStream_t stream) {
  const float* x     = (const float*)d_in[0];
  const float* ln1g  = (const float*)d_in[1];
  const float* ln1b  = (const float*)d_in[2];
  const float* wqkv  = (const float*)d_in[3];
  const float* wproj = (const float*)d_in[4];
  const float* ln2g  = (const float*)d_in[5];
  const float* ln2b  = (const float*)d_in[6];
  const float* wff1  = (const float*)d_in[7];
  const float* wff2  = (const float*)d_in[8];
  float* out = (float*)d_out;
  char* ws = (char*)d_ws;

  u16* wt_qkv  = (u16*)(ws);
  u16* wt_proj = (u16*)(ws + 1572864);
  u16* wt_ff1  = (u16*)(ws + 2097152);
  u16* wt_ff2  = (u16*)(ws + 4194304);
  u16* ln_buf  = (u16*)(ws + 6291456);
  u16* q_buf   = (u16*)(ws + 14680064);
  u16* k_buf   = (u16*)(ws + 23068672);
  u16* vt_buf  = (u16*)(ws + 31457280);
  u16* attn    = (u16*)(ws + 39845888);
  float* x2    = (float*)(ws + 48234496);
  u16* h1      = (u16*)(ws + 65011712);
  u16* po      = (u16*)(ws + 48234496);
  float* pl    = (float*)(ws + 85983232);

  dim3 blk(256);
  prep_kernel<<<dim3(5120), blk, 0, stream>>>(x, ln1g, ln1b, wqkv, wproj, wff1, wff2,
                                              ln_buf, wt_qkv, wt_proj, wt_ff1, wt_ff2);

  // QKV: 2D grid (R12-proven for short-K)
  gemm_kernel<0, 128, 64, 6, 0><<<dim3(CQKV / 64, BT / 128), blk, 0, stream>>>(
      ln_buf, wt_qkv, CMOD, nullptr, nullptr, q_buf, k_buf, vt_buf);

  // attn: grid 2304 x 128 threads (2 waves x 32 q-rows), XCD swizzle (bh = n & 15)
  attn_kernel<<<dim3(2304), dim3(128), 0, stream>>>(q_buf, k_buf, vt_buf, po, pl);

  reduce_kernel<<<dim3(512), blk, 0, stream>>>(po, pl, attn);

  // proj: 1D XCD-swizzled grid (R13-proven for fat-A reuse)
  gemm_kernel<1, 128, 64, 4, 1><<<dim3((CMOD / 64) * 64), blk, 0, stream>>>(
      attn, wt_proj, CMOD, x, x2, nullptr, nullptr, nullptr);

  ln_kernel<<<dim3(BT / 4), blk, 0, stream>>>(x2, ln2g, ln2b, ln_buf);

  // FF1: 2D grid (R12-proven; 1D swizzle regressed it 44.8 -> 52)
  gemm_kernel<2, 128, 64, 6, 0><<<dim3(DFF / 64, BT / 128), blk, 0, stream>>>(
      ln_buf, wt_ff1, CMOD, nullptr, nullptr, h1, nullptr, nullptr);

  // FF2: 1D XCD-swizzled grid (R13-proven: FETCH 140 -> ~55MB)
  gemm_kernel<3, 128, 64, 4, 1><<<dim3((CMOD / 64) * 64), blk, 0, stream>>>(
      h1, wt_ff2, DFF, x2, out, nullptr, nullptr, nullptr);
}

// Round 15
// 254.449 us; speedup vs baseline: 1.0001x; 1.0001x over previous
//
#include <hip/hip_runtime.h>
#include <cstdint>

typedef unsigned short u16;
typedef __attribute__((ext_vector_type(8))) short short8;
typedef __attribute__((ext_vector_type(4))) float floatx4;

#define BT    8192
#define TSEQ  2048
#define NBAT  4
#define CMOD  512
#define NH    4
#define HD    128
#define DFF   2048
#define CQKV  1536

__device__ __forceinline__ u16 f2bf(float f) {
  union { float f; uint32_t u; } v; v.f = f;
  uint32_t r = v.u + 0x7FFFu + ((v.u >> 16) & 1u);
  return (u16)(r >> 16);
}
__device__ __forceinline__ float bf2f(u16 u) {
  union { uint32_t u; float f; } v; v.u = ((uint32_t)u) << 16; return v.f;
}
__device__ __forceinline__ float exp2a(float x) {
  float r; asm("v_exp_f32 %0, %1" : "=v"(r) : "v"(x)); return r;
}
__device__ __forceinline__ float rcpa(float x) {
  float r; asm("v_rcp_f32 %0, %1" : "=v"(r) : "v"(x)); return r;
}

typedef __attribute__((address_space(1))) const unsigned int ga_u32;
typedef __attribute__((address_space(3))) unsigned int ls_u32;
__device__ __forceinline__ void glds16(const u16* g, u16* l) {
  __builtin_amdgcn_global_load_lds((ga_u32*)g, (ls_u32*)l, 16, 0, 0);
}

// AF/BF fragment-blocked layout for K=512 (NKT=16 k-tiles):
//   (row, k) -> [((row>>4)*16 + (k>>5))*512 + ((k>>3)&3)*128 + (row&15)*8 + (k&7)]
// A wave's fragment load is then base + lane*8 (dense 1KB per wave) since
// lane*8 = quad*128 + lane16*8.
__device__ __forceinline__ size_t af_idx(int row, int k, int nkt) {
  return (size_t)((row >> 4) * nkt + (k >> 5)) * 512 + ((k >> 3) & 3) * 128 + (row & 15) * 8 + (k & 7);
}

// ---------------- fused prep: 4 weight transposes + LN1 ----------------
// BFMT=1 emits the fragment-blocked layout (for wqkv, wff1 -> consumed by gemm_frag).
__device__ __forceinline__ void tcast_body(const float* __restrict__ W, u16* __restrict__ Wt,
                                           int K, int N, int bx, int by, int tid,
                                           float (*tile)[33], int BFMT) {
  int n0 = bx * 32, k0 = by * 32;
  int tx = tid & 31, ty = tid >> 5;
  #pragma unroll
  for (int r = 0; r < 32; r += 8)
    tile[r + ty][tx] = W[(size_t)(k0 + r + ty) * N + n0 + tx];
  __syncthreads();
  #pragma unroll
  for (int r = 0; r < 32; r += 8) {
    int nr = n0 + r + ty, k = k0 + tx;
    if (BFMT)
      Wt[af_idx(nr, k, K >> 5)] = f2bf(tile[tx][r + ty]);
    else
      Wt[(size_t)nr * K + k] = f2bf(tile[tx][r + ty]);
  }
}

__global__ __launch_bounds__(256) void prep_kernel(
    const float* __restrict__ x, const float* __restrict__ g, const float* __restrict__ b,
    const float* __restrict__ wqkv, const float* __restrict__ wproj,
    const float* __restrict__ wff1, const float* __restrict__ wff2,
    u16* __restrict__ ln_out, u16* __restrict__ wqkvT, u16* __restrict__ wprojT,
    u16* __restrict__ wff1T, u16* __restrict__ wff2T) {
  __shared__ float tile[32][33];
  int bid = blockIdx.x, tid = threadIdx.x;
  if (bid < 768) {
    tcast_body(wqkv, wqkvT, CMOD, CQKV, bid % 48, bid / 48, tid, tile, 1);
  } else if (bid < 1024) {
    int id = bid - 768; tcast_body(wproj, wprojT, CMOD, CMOD, id % 16, id / 16, tid, tile, 0);
  } else if (bid < 2048) {
    int id = bid - 1024; tcast_body(wff1, wff1T, CMOD, DFF, id % 64, id / 64, tid, tile, 1);
  } else if (bid < 3072) {
    int id = bid - 2048; tcast_body(wff2, wff2T, DFF, CMOD, id % 16, id / 16, tid, tile, 0);
  } else {
    int row = (bid - 3072) * 4 + (tid >> 6);
    int lane = tid & 63;
    const float4* xr = (const float4*)(x + (size_t)row * CMOD);
    float4 a = xr[lane], c = xr[lane + 64];
    float s = a.x + a.y + a.z + a.w + c.x + c.y + c.z + c.w;
    float q = a.x*a.x + a.y*a.y + a.z*a.z + a.w*a.w
            + c.x*c.x + c.y*c.y + c.z*c.z + c.w*c.w;
    #pragma unroll
    for (int o = 32; o; o >>= 1) { s += __shfl_xor(s, o); q += __shfl_xor(q, o); }
    float mu = s * (1.0f / CMOD);
    float rstd = rsqrtf(q * (1.0f / CMOD) - mu * mu + 1e-5f);
    const float4* gr = (const float4*)g;
    const float4* br = (const float4*)b;
    float4 g0 = gr[lane], g1 = gr[lane + 64], b0 = br[lane], b1 = br[lane + 64];
    // AF-layout store (ln_buf consumed by gemm_frag QKV)
    int c0 = lane * 4, c1 = (lane + 64) * 4;
    u16* o0 = ln_out + af_idx(row, c0, 16);
    u16* o1 = ln_out + af_idx(row, c1, 16);
    o0[0] = f2bf((a.x - mu) * rstd * g0.x + b0.x);
    o0[1] = f2bf((a.y - mu) * rstd * g0.y + b0.y);
    o0[2] = f2bf((a.z - mu) * rstd * g0.z + b0.z);
    o0[3] = f2bf((a.w - mu) * rstd * g0.w + b0.w);
    o1[0] = f2bf((c.x - mu) * rstd * g1.x + b1.x);
    o1[1] = f2bf((c.y - mu) * rstd * g1.y + b1.y);
    o1[2] = f2bf((c.z - mu) * rstd * g1.z + b1.z);
    o1[3] = f2bf((c.w - mu) * rstd * g1.w + b1.w);
  }
}

// ---------------- layernorm (LN2 -> AF layout for gemm_frag FF1) ----------------
__global__ __launch_bounds__(256) void ln_kernel(const float* __restrict__ x,
                                                 const float* __restrict__ g,
                                                 const float* __restrict__ b,
                                                 u16* __restrict__ out) {
  int row = blockIdx.x * 4 + (threadIdx.x >> 6);
  int lane = threadIdx.x & 63;
  const float4* xr = (const float4*)(x + (size_t)row * CMOD);
  float4 a = xr[lane], c = xr[lane + 64];
  float s = a.x + a.y + a.z + a.w + c.x + c.y + c.z + c.w;
  float q = a.x*a.x + a.y*a.y + a.z*a.z + a.w*a.w
          + c.x*c.x + c.y*c.y + c.z*c.z + c.w*c.w;
  #pragma unroll
  for (int o = 32; o; o >>= 1) { s += __shfl_xor(s, o); q += __shfl_xor(q, o); }
  float mu = s * (1.0f / CMOD);
  float rstd = rsqrtf(q * (1.0f / CMOD) - mu * mu + 1e-5f);
  const float4* gr = (const float4*)g;
  const float4* br = (const float4*)b;
  float4 g0 = gr[lane], g1 = gr[lane + 64], b0 = br[lane], b1 = br[lane + 64];
  int c0 = lane * 4, c1 = (lane + 64) * 4;
  u16* o0 = out + af_idx(row, c0, 16);
  u16* o1 = out + af_idx(row, c1, 16);
  o0[0] = f2bf((a.x - mu) * rstd * g0.x + b0.x);
  o0[1] = f2bf((a.y - mu) * rstd * g0.y + b0.y);
  o0[2] = f2bf((a.z - mu) * rstd * g0.z + b0.z);
  o0[3] = f2bf((a.w - mu) * rstd * g0.w + b0.w);
  o1[0] = f2bf((c.x - mu) * rstd * g1.x + b1.x);
  o1[1] = f2bf((c.y - mu) * rstd * g1.y + b1.y);
  o1[2] = f2bf((c.z - mu) * rstd * g1.z + b1.z);
  o1[3] = f2bf((c.w - mu) * rstd * g1.w + b1.w);
}

// ---------------- NEW: LDS-free streaming GEMM on fragment-blocked operands ----------------
// QKV + FF1 (both K=512). No LDS, no barriers: every fragment is a dense
// lane-contiguous 1KB wave-load from AF/BF; waves free-run; compiler pipelines
// across k (register deps only). Wave tile 64x64 (acc[4][4], 16 MFMA / 8 loads
// per k-tile). Block 128x128; 1D grid with m-block in low bits -> panel sharers
// on one XCD (A-set 1MB + B 2MB < 4MB L2). Same fragment values + k-ascending
// accumulation as the LDS kernel -> bit-identical output.
template <int EPI>
__global__ __launch_bounds__(256) void gemm_frag(
    const u16* __restrict__ AF, const u16* __restrict__ BF,
    u16* __restrict__ ob0, u16* __restrict__ ob1, u16* __restrict__ ob2) {
  int tid = threadIdx.x;
  int lane = tid & 63, wave = tid >> 6;
  int lane16 = lane & 15, quad = lane >> 4;
  int mb = blockIdx.x & 63, nb = blockIdx.x >> 6;
  int mw = mb * 128 + (wave >> 1) * 64;
  int nw = nb * 128 + (wave & 1) * 64;
  const u16* ap = AF + (size_t)mw * 512 + lane * 8;
  const u16* bp = BF + (size_t)nw * 512 + lane * 8;

  floatx4 acc[4][4];
  #pragma unroll
  for (int i = 0; i < 4; i++)
    #pragma unroll
    for (int j = 0; j < 4; j++) acc[i][j] = (floatx4)(0.0f);

  for (int kt = 0; kt < 16; kt++) {
    short8 af[4], bf[4];
    #pragma unroll
    for (int i = 0; i < 4; i++)
      af[i] = *(const short8*)(ap + (size_t)(i * 16 + kt) * 512);
    #pragma unroll
    for (int j = 0; j < 4; j++)
      bf[j] = *(const short8*)(bp + (size_t)(j * 16 + kt) * 512);
    #pragma unroll
    for (int j = 0; j < 4; j++)
      #pragma unroll
      for (int i = 0; i < 4; i++)
        acc[i][j] = __builtin_amdgcn_mfma_f32_16x16x32_bf16(af[i], bf[j], acc[i][j], 0, 0, 0);
  }

  #pragma unroll
  for (int i = 0; i < 4; i++) {
    #pragma unroll
    for (int j = 0; j < 4; j++) {
      #pragma unroll
      for (int r = 0; r < 4; r++) {
        int m = mw + i * 16 + quad * 4 + r;
        int n = nw + j * 16 + lane16;
        float v = acc[i][j][r];
        if (EPI == 0) {
          int bb = m >> 11, t = m & 2047;
          int nn = n & 511, which = n >> 9;
          int h = nn >> 7, d = nn & 127;
          size_t base = (size_t)(bb * NH + h) * 262144;
          if (which == 0) {
            int t16 = t >> 4, l16 = t & 15, cc = d >> 5, qd = (d >> 3) & 3, e = d & 7;
            ob0[base + (size_t)((t16 * 16 + cc * 4 + qd) * 128 + l16 * 8 + e)] = f2bf(v * 0.12751743f);
          } else if (which == 1) {
            int kt2 = t >> 5, hf = (t >> 4) & 1, l16 = t & 15, cc = d >> 5, qd = (d >> 3) & 3, e = d & 7;
            ob1[base + (size_t)((kt2 * 8 + hf * 4 + cc) * 512 + qd * 128 + l16 * 8 + e)] = f2bf(v);
          } else {
            int kt2 = t >> 5, qv = (t >> 3) & 3, e = t & 7, j2 = d >> 4, l16 = d & 15;
            ob2[base + (size_t)((kt2 * 8 + j2) * 512 + qv * 128 + l16 * 8 + e)] = f2bf(v);
          }
        } else {
          float ge = 0.5f * v * (1.0f + erff(v * 0.70710678118654752f));
          ob0[(size_t)m * DFF + n] = f2bf(ge);
        }
      }
    }
  }
}

// ---------------- LDS GEMM (proj, FF2 — R13 1D-swizzled config, frozen) ----------------
template <int EPI, int TM, int TN, int MINW>
__global__ __launch_bounds__(256, MINW) void gemm_kernel(
    const u16* __restrict__ A, const u16* __restrict__ Bt, int K,
    const float* __restrict__ resid, float* __restrict__ outf) {
  constexpr int MR  = TM / 32;
  constexpr int NR  = TN / 32;
  constexpr int NAR = TM / 64;
  constexpr int NBR = TN / 64;
  __shared__ __align__(16) u16 As[2][TM * 32];
  __shared__ __align__(16) u16 Bs[2][TN * 32];
  int tid = threadIdx.x;
  int lane = tid & 63, wave = tid >> 6;
  int lane16 = lane & 15, quad = lane >> 4;
  int n1d = blockIdx.x;
  int m0 = (n1d & 63) * TM;
  int n0 = (n1d >> 6) * TN;
  int wm = (wave >> 1) * (TM / 2), wn = (wave & 1) * (TN / 2);

  floatx4 acc[MR][NR];
  #pragma unroll
  for (int i = 0; i < MR; i++)
    #pragma unroll
    for (int j = 0; j < NR; j++) acc[i][j] = (floatx4)(0.0f);

  const u16* agp[NAR]; u16* alp[NAR][2];
  const u16* bgp[NBR]; u16* blp[NBR][2];
  #pragma unroll
  for (int i = 0; i < NAR; i++) {
    int s = i * 256 + tid;
    agp[i] = A + (size_t)(m0 + (s >> 2)) * K + (s & 3) * 8;
    alp[i][0] = &As[0][(i * 256 + wave * 64) * 8];
    alp[i][1] = &As[1][(i * 256 + wave * 64) * 8];
  }
  #pragma unroll
  for (int i = 0; i < NBR; i++) {
    int s = i * 256 + tid;
    bgp[i] = Bt + (size_t)(n0 + (s >> 2)) * K + (s & 3) * 8;
    blp[i][0] = &Bs[0][(i * 256 + wave * 64) * 8];
    blp[i][1] = &Bs[1][(i * 256 + wave * 64) * 8];
  }

  int nk = K >> 5;
  #pragma unroll
  for (int i = 0; i < NAR; i++) glds16(agp[i], alp[i][0]);
  #pragma unroll
  for (int i = 0; i < NBR; i++) glds16(bgp[i], blp[i][0]);

  for (int kt = 0; kt < nk; kt++) {
    __syncthreads();
    int buf = kt & 1;
    if (kt + 1 < nk) {
      int k1 = (kt + 1) * 32;
      #pragma unroll
      for (int i = 0; i < NAR; i++) glds16(agp[i] + k1, alp[i][buf ^ 1]);
      #pragma unroll
      for (int i = 0; i < NBR; i++) glds16(bgp[i] + k1, blp[i][buf ^ 1]);
    }
    short8 af[MR];
    #pragma unroll
    for (int i = 0; i < MR; i++)
      af[i] = *(const short8*)&As[buf][(wm + i * 16 + lane16) * 32 + quad * 8];
    #pragma unroll
    for (int j = 0; j < NR; j++) {
      short8 bfj = *(const short8*)&Bs[buf][(wn + j * 16 + lane16) * 32 + quad * 8];
      #pragma unroll
      for (int i = 0; i < MR; i++)
        acc[i][j] = __builtin_amdgcn_mfma_f32_16x16x32_bf16(af[i], bfj, acc[i][j], 0, 0, 0);
    }
  }

  #pragma unroll
  for (int i = 0; i < MR; i++) {
    #pragma unroll
    for (int j = 0; j < NR; j++) {
      #pragma unroll
      for (int r = 0; r < 4; r++) {
        int m = m0 + wm + i * 16 + quad * 4 + r;
        int n = n0 + wn + j * 16 + lane16;
        float v = acc[i][j][r];
        size_t idx = (size_t)m * CMOD + n;
        outf[idx] = v + resid[idx];
      }
    }
  }
}

// ---------------- flash attention: R12 (frozen) ----------------
__global__ __launch_bounds__(128) void attn_kernel(const u16* __restrict__ qb,
                                                   const u16* __restrict__ kb,
                                                   const u16* __restrict__ vtb,
                                                   u16* __restrict__ po,
                                                   float* __restrict__ pl) {
  int tid = threadIdx.x, wave = tid >> 6, lane = tid & 63;
  int lane16 = lane & 15, quad = lane >> 4;
  int n1d = blockIdx.x;
  int bh = n1d & 15;
  int idx = 143 - (n1d >> 4);   // heavy (large qt) chunks dispatch first
  int g = 1;
  #pragma unroll
  for (int t = 2; t <= 8; t++) if (idx >= 2 * t * (t - 1)) g = t;
  int rem = idx - 2 * g * (g - 1);
  int qi = rem / g;
  int c  = rem - qi * g;
  int qt = ((g - 1) << 2) + qi;

  int q0w = qt * 64 + wave * 32;   // 32 rows per wave
  const u16* Qb = qb  + (size_t)bh * 262144;
  const u16* Kb = kb  + (size_t)bh * 262144;
  const u16* Vb = vtb + (size_t)bh * 262144;

  short8 aqA[4], aqB[4];
  {
    int t16 = q0w >> 4;
    #pragma unroll
    for (int cc = 0; cc < 4; cc++) {
      aqA[cc] = *(const short8*)&Qb[(size_t)((t16 * 16 + cc * 4 + quad) * 128 + lane16 * 8)];
      aqB[cc] = *(const short8*)&Qb[(size_t)(((t16 + 1) * 16 + cc * 4 + quad) * 128 + lane16 * 8)];
    }
  }

  int ktw   = (q0w >> 5) + 1;
  int ktblk = qt * 2 + 2;
  int kt0   = c * 8;
  int kend  = min(min(kt0 + 8, ktblk), ktw);

  floatx4 oA[8], oB[8];
  #pragma unroll
  for (int j = 0; j < 8; j++) { oA[j] = (floatx4)(0.0f); oB[j] = (floatx4)(0.0f); }
  floatx4 olA = (floatx4)(0.0f), olB = (floatx4)(0.0f);

  short8 ones;
  #pragma unroll
  for (int e = 0; e < 8; e++) ones[e] = (short)0x3F80;

  int addrA = (lane16 + ((quad & 1) << 5)) << 2;
  int addrB = addrA + 64;
  int q_gA = q0w + lane16;
  int q_gB = q0w + 16 + lane16;

#define ATTN_TAIL(S0, S1, O_, OL_, QG, KT)                                                          \
  {                                                                                                 \
    int k0b = (KT) * 32 + quad * 4;                                                                 \
    _Pragma("unroll")                                                                               \
    for (int r = 0; r < 4; r++) {                                                                   \
      float p0 = exp2a(S0[r]);                                                                      \
      float p1 = exp2a(S1[r]);                                                                      \
      if (k0b + r > (QG)) p0 = 0.0f;                                                                \
      if (k0b + r + 16 > (QG)) p1 = 0.0f;                                                           \
      S0[r] = p0; S1[r] = p1;                                                                       \
    }                                                                                               \
    uint32_t x0 = __builtin_amdgcn_perm(__float_as_uint(S0[1]), __float_as_uint(S0[0]), 0x07060302u); \
    uint32_t x1 = __builtin_amdgcn_perm(__float_as_uint(S0[3]), __float_as_uint(S0[2]), 0x07060302u); \
    uint32_t y0 = __builtin_amdgcn_perm(__float_as_uint(S1[1]), __float_as_uint(S1[0]), 0x07060302u); \
    uint32_t y1 = __builtin_amdgcn_perm(__float_as_uint(S1[3]), __float_as_uint(S1[2]), 0x07060302u); \
    int pAx0 = __builtin_amdgcn_ds_bpermute(addrA, (int)x0);                                        \
    int pAx1 = __builtin_amdgcn_ds_bpermute(addrA, (int)x1);                                        \
    int pBx0 = __builtin_amdgcn_ds_bpermute(addrB, (int)x0);                                        \
    int pBx1 = __builtin_amdgcn_ds_bpermute(addrB, (int)x1);                                        \
    int pAy0 = __builtin_amdgcn_ds_bpermute(addrA, (int)y0);                                        \
    int pAy1 = __builtin_amdgcn_ds_bpermute(addrA, (int)y1);                                        \
    int pBy0 = __builtin_amdgcn_ds_bpermute(addrB, (int)y0);                                        \
    int pBy1 = __builtin_amdgcn_ds_bpermute(addrB, (int)y1);                                        \
    union { uint32_t u[4]; short8 s; } pf;                                                          \
    bool hi = quad >= 2;                                                                            \
    pf.u[0] = (uint32_t)(hi ? pAy0 : pAx0);                                                         \
    pf.u[1] = (uint32_t)(hi ? pAy1 : pAx1);                                                         \
    pf.u[2] = (uint32_t)(hi ? pBy0 : pBx0);                                                         \
    pf.u[3] = (uint32_t)(hi ? pBy1 : pBx1);                                                         \
    _Pragma("unroll")                                                                               \
    for (int j = 0; j < 8; j++)                                                                     \
      O_[j] = __builtin_amdgcn_mfma_f32_16x16x32_bf16(pf.s, vfr[j], O_[j], 0, 0, 0);                \
    OL_ = __builtin_amdgcn_mfma_f32_16x16x32_bf16(pf.s, ones, OL_, 0, 0, 0);                        \
  }

  for (int kt = kt0; kt < kend; kt++) {
    const u16* kp = Kb + (size_t)kt * 4096 + lane * 8;
    const u16* vp = Vb + (size_t)kt * 4096 + lane * 8;
    short8 k0f[4], k1f[4];
    #pragma unroll
    for (int cc = 0; cc < 4; cc++) {
      k0f[cc] = *(const short8*)&kp[cc * 512];
      k1f[cc] = *(const short8*)&kp[(4 + cc) * 512];
    }

    floatx4 sA0 = (floatx4)(0.0f), sA1 = (floatx4)(0.0f);
    floatx4 sB0 = (floatx4)(0.0f), sB1 = (floatx4)(0.0f);
    #pragma unroll
    for (int cc = 0; cc < 4; cc++) {
      sA0 = __builtin_amdgcn_mfma_f32_16x16x32_bf16(k0f[cc], aqA[cc], sA0, 0, 0, 0);
      sA1 = __builtin_amdgcn_mfma_f32_16x16x32_bf16(k1f[cc], aqA[cc], sA1, 0, 0, 0);
      sB0 = __builtin_amdgcn_mfma_f32_16x16x32_bf16(k0f[cc], aqB[cc], sB0, 0, 0, 0);
      sB1 = __builtin_amdgcn_mfma_f32_16x16x32_bf16(k1f[cc], aqB[cc], sB1, 0, 0, 0);
    }

    short8 vfr[8];
    #pragma unroll
    for (int j = 0; j < 8; j++)
      vfr[j] = *(const short8*)&vp[j * 512];

    ATTN_TAIL(sA0, sA1, oA, olA, q_gA, kt);
    ATTN_TAIL(sB0, sB1, oB, olB, q_gB, kt);
  }
#undef ATTN_TAIL

  int slot = bh * 144 + 2 * g * (g - 1) + qi * g + c;
  u16* pob = po + (size_t)slot * 8192;
  #pragma unroll
  for (int r = 0; r < 4; r++) {
    int qrA = wave * 32 + quad * 4 + r;
    int qrB = qrA + 16;
    #pragma unroll
    for (int j = 0; j < 8; j++) {
      pob[qrA * 128 + j * 16 + lane16] = f2bf(oA[j][r]);
      pob[qrB * 128 + j * 16 + lane16] = f2bf(oB[j][r]);
    }
    if (lane16 == 0) {
      pl[slot * 64 + qrA] = olA[r];
      pl[slot * 64 + qrB] = olB[r];
    }
  }
}

// ---------------- reduce: R11 slot mapping (frozen) ----------------
__global__ __launch_bounds__(256) void reduce_kernel(const u16* __restrict__ po,
                                                     const float* __restrict__ pl,
                                                     u16* __restrict__ attn) {
  int bh = blockIdx.x >> 5, qt = blockIdx.x & 31;
  int tid = threadIdx.x;
  int g = (qt >> 2) + 1;
  int slot0 = bh * 144 + 2 * g * (g - 1) + (qt & 3) * g;
  int qrow = tid >> 2;
  int d0 = (tid & 3) * 32;
  float acc[32];
  #pragma unroll
  for (int i = 0; i < 32; i++) acc[i] = 0.0f;
  float l = 0.0f;
  for (int c = 0; c < g; c++) {
    int slot = slot0 + c;
    l += pl[slot * 64 + qrow];
    const short8* p = (const short8*)(po + (size_t)slot * 8192 + qrow * 128 + d0);
    #pragma unroll
    for (int v = 0; v < 4; v++) {
      short8 pk = p[v];
      #pragma unroll
      for (int e = 0; e < 8; e++) acc[v * 8 + e] += bf2f((u16)pk[e]);
    }
  }
  float inv = rcpa(l);
  int b = bh >> 2, h = bh & 3, t = qt * 64 + qrow;
  u16* orow = attn + ((size_t)(b * TSEQ + t)) * CMOD + h * HD + d0;
  #pragma unroll
  for (int v = 0; v < 4; v++) {
    short8 ov;
    #pragma unroll
    for (int e = 0; e < 8; e++) ov[e] = (short)f2bf(acc[v * 8 + e] * inv);
    *(short8*)(orow + v * 8) = ov;
  }
}

extern "C" void kernel_launch(void* const* d_in, const int* in_sizes, int n_in,
                              void* d_out, int out_size, void* d_ws, size_t ws_size,
                              hipStream_t stream) {
  const float* x     = (const float*)d_in[0];
  const float* ln1g  = (const float*)d_in[1];
  const float* ln1b  = (const float*)d_in[2];
  const float* wqkv  = (const float*)d_in[3];
  const float* wproj = (const float*)d_in[4];
  const float* ln2g  = (const float*)d_in[5];
  const float* ln2b  = (const float*)d_in[6];
  const float* wff1  = (const float*)d_in[7];
  const float* wff2  = (const float*)d_in[8];
  float* out = (float*)d_out;
  char* ws = (char*)d_ws;

  u16* wt_qkv  = (u16*)(ws);
  u16* wt_proj = (u16*)(ws + 1572864);
  u16* wt_ff1  = (u16*)(ws + 2097152);
  u16* wt_ff2  = (u16*)(ws + 4194304);
  u16* ln_buf  = (u16*)(ws + 6291456);
  u16* q_buf   = (u16*)(ws + 14680064);
  u16* k_buf   = (u16*)(ws + 23068672);
  u16* vt_buf  = (u16*)(ws + 31457280);
  u16* attn    = (u16*)(ws + 39845888);
  float* x2    = (float*)(ws + 48234496);
  u16* h1      = (u16*)(ws + 65011712);
  u16* po      = (u16*)(ws + 48234496);
  float* pl    = (float*)(ws + 85983232);

  dim3 blk(256);
  prep_kernel<<<dim3(5120), blk, 0, stream>>>(x, ln1g, ln1b, wqkv, wproj, wff1, wff2,
                                              ln_buf, wt_qkv, wt_proj, wt_ff1, wt_ff2);

  // QKV: LDS-free streaming GEMM, grid 64 m-blocks x 12 n-blocks = 768 (m in low bits)
  gemm_frag<0><<<dim3(768), blk, 0, stream>>>(ln_buf, wt_qkv, q_buf, k_buf, vt_buf);

  // attn: grid 2304 x 128 threads (2 waves x 32 q-rows), XCD swizzle (bh = n & 15)
  attn_kernel<<<dim3(2304), dim3(128), 0, stream>>>(q_buf, k_buf, vt_buf, po, pl);

  reduce_kernel<<<dim3(512), blk, 0, stream>>>(po, pl, attn);

  // proj: LDS GEMM, 1D XCD-swizzled grid (R13-proven)
  gemm_kernel<1, 128, 64, 4><<<dim3((CMOD / 64) * 64), blk, 0, stream>>>(
      attn, wt_proj, CMOD, x, x2);

  ln_kernel<<<dim3(BT / 4), blk, 0, stream>>>(x2, ln2g, ln2b, ln_buf);

  // FF1: LDS-free streaming GEMM, grid 64 x 16 = 1024 (m in low bits)
  gemm_frag<2><<<dim3(1024), blk, 0, stream>>>(ln_buf, wt_ff1, h1, nullptr, nullptr);

  // FF2: LDS GEMM, 1D XCD-swizzled grid (R13-proven)
  gemm_kernel<3, 128, 64, 4><<<dim3((CMOD / 64) * 64), blk, 0, stream>>>(
      h1, wt_ff2, DFF, x2, out);
}

// Round 16
// 250.702 us; speedup vs baseline: 1.0150x; 1.0149x over previous
//
#include <hip/hip_runtime.h>
#include <cstdint>

typedef unsigned short u16;
typedef __attribute__((ext_vector_type(8))) short short8;
typedef __attribute__((ext_vector_type(4))) float floatx4;

#define BT    8192
#define TSEQ  2048
#define NBAT  4
#define CMOD  512
#define NH    4
#define HD    128
#define DFF   2048
#define CQKV  1536

__device__ __forceinline__ u16 f2bf(float f) {
  union { float f; uint32_t u; } v; v.f = f;
  uint32_t r = v.u + 0x7FFFu + ((v.u >> 16) & 1u);
  return (u16)(r >> 16);
}
__device__ __forceinline__ float bf2f(u16 u) {
  union { uint32_t u; float f; } v; v.u = ((uint32_t)u) << 16; return v.f;
}
__device__ __forceinline__ float exp2a(float x) {
  float r; asm("v_exp_f32 %0, %1" : "=v"(r) : "v"(x)); return r;
}
__device__ __forceinline__ float rcpa(float x) {
  float r; asm("v_rcp_f32 %0, %1" : "=v"(r) : "v"(x)); return r;
}

typedef __attribute__((address_space(1))) const unsigned int ga_u32;
typedef __attribute__((address_space(3))) unsigned int ls_u32;
__device__ __forceinline__ void glds16(const u16* g, u16* l) {
  __builtin_amdgcn_global_load_lds((ga_u32*)g, (ls_u32*)l, 16, 0, 0);
}

// ---------------- fused prep: 4 weight transposes + LN1 (R13 exact) ----------------
__device__ __forceinline__ void tcast_body(const float* __restrict__ W, u16* __restrict__ Wt,
                                           int K, int N, int bx, int by, int tid,
                                           float (*tile)[33]) {
  int n0 = bx * 32, k0 = by * 32;
  int tx = tid & 31, ty = tid >> 5;
  #pragma unroll
  for (int r = 0; r < 32; r += 8)
    tile[r + ty][tx] = W[(size_t)(k0 + r + ty) * N + n0 + tx];
  __syncthreads();
  #pragma unroll
  for (int r = 0; r < 32; r += 8)
    Wt[(size_t)(n0 + r + ty) * K + k0 + tx] = f2bf(tile[tx][r + ty]);
}

__global__ __launch_bounds__(256) void prep_kernel(
    const float* __restrict__ x, const float* __restrict__ g, const float* __restrict__ b,
    const float* __restrict__ wqkv, const float* __restrict__ wproj,
    const float* __restrict__ wff1, const float* __restrict__ wff2,
    u16* __restrict__ ln_out, u16* __restrict__ wqkvT, u16* __restrict__ wprojT,
    u16* __restrict__ wff1T, u16* __restrict__ wff2T) {
  __shared__ float tile[32][33];
  int bid = blockIdx.x, tid = threadIdx.x;
  if (bid < 768) {
    tcast_body(wqkv, wqkvT, CMOD, CQKV, bid % 48, bid / 48, tid, tile);
  } else if (bid < 1024) {
    int id = bid - 768; tcast_body(wproj, wprojT, CMOD, CMOD, id % 16, id / 16, tid, tile);
  } else if (bid < 2048) {
    int id = bid - 1024; tcast_body(wff1, wff1T, CMOD, DFF, id % 64, id / 64, tid, tile);
  } else if (bid < 3072) {
    int id = bid - 2048; tcast_body(wff2, wff2T, DFF, CMOD, id % 16, id / 16, tid, tile);
  } else {
    int row = (bid - 3072) * 4 + (tid >> 6);
    int lane = tid & 63;
    const float4* xr = (const float4*)(x + (size_t)row * CMOD);
    float4 a = xr[lane], c = xr[lane + 64];
    float s = a.x + a.y + a.z + a.w + c.x + c.y + c.z + c.w;
    float q = a.x*a.x + a.y*a.y + a.z*a.z + a.w*a.w
            + c.x*c.x + c.y*c.y + c.z*c.z + c.w*c.w;
    #pragma unroll
    for (int o = 32; o; o >>= 1) { s += __shfl_xor(s, o); q += __shfl_xor(q, o); }
    float mu = s * (1.0f / CMOD);
    float rstd = rsqrtf(q * (1.0f / CMOD) - mu * mu + 1e-5f);
    const float4* gr = (const float4*)g;
    const float4* br = (const float4*)b;
    float4 g0 = gr[lane], g1 = gr[lane + 64], b0 = br[lane], b1 = br[lane + 64];
    u16* orow = ln_out + (size_t)row * CMOD;
    int i0 = lane * 4, i1 = (lane + 64) * 4;
    orow[i0 + 0] = f2bf((a.x - mu) * rstd * g0.x + b0.x);
    orow[i0 + 1] = f2bf((a.y - mu) * rstd * g0.y + b0.y);
    orow[i0 + 2] = f2bf((a.z - mu) * rstd * g0.z + b0.z);
    orow[i0 + 3] = f2bf((a.w - mu) * rstd * g0.w + b0.w);
    orow[i1 + 0] = f2bf((c.x - mu) * rstd * g1.x + b1.x);
    orow[i1 + 1] = f2bf((c.y - mu) * rstd * g1.y + b1.y);
    orow[i1 + 2] = f2bf((c.z - mu) * rstd * g1.z + b1.z);
    orow[i1 + 3] = f2bf((c.w - mu) * rstd * g1.w + b1.w);
  }
}

// ---------------- layernorm (standalone, for LN2; R13 exact) ----------------
__global__ __launch_bounds__(256) void ln_kernel(const float* __restrict__ x,
                                                 const float* __restrict__ g,
                                                 const float* __restrict__ b,
                                                 u16* __restrict__ out) {
  int row = blockIdx.x * 4 + (threadIdx.x >> 6);
  int lane = threadIdx.x & 63;
  const float4* xr = (const float4*)(x + (size_t)row * CMOD);
  float4 a = xr[lane], c = xr[lane + 64];
  float s = a.x + a.y + a.z + a.w + c.x + c.y + c.z + c.w;
  float q = a.x*a.x + a.y*a.y + a.z*a.z + a.w*a.w
          + c.x*c.x + c.y*c.y + c.z*c.z + c.w*c.w;
  #pragma unroll
  for (int o = 32; o; o >>= 1) { s += __shfl_xor(s, o); q += __shfl_xor(q, o); }
  float mu = s * (1.0f / CMOD);
  float rstd = rsqrtf(q * (1.0f / CMOD) - mu * mu + 1e-5f);
  const float4* gr = (const float4*)g;
  const float4* br = (const float4*)b;
  float4 g0 = gr[lane], g1 = gr[lane + 64], b0 = br[lane], b1 = br[lane + 64];
  u16* orow = out + (size_t)row * CMOD;
  int i0 = lane * 4, i1 = (lane + 64) * 4;
  orow[i0 + 0] = f2bf((a.x - mu) * rstd * g0.x + b0.x);
  orow[i0 + 1] = f2bf((a.y - mu) * rstd * g0.y + b0.y);
  orow[i0 + 2] = f2bf((a.z - mu) * rstd * g0.z + b0.z);
  orow[i0 + 3] = f2bf((a.w - mu) * rstd * g0.w + b0.w);
  orow[i1 + 0] = f2bf((c.x - mu) * rstd * g1.x + b1.x);
  orow[i1 + 1] = f2bf((c.y - mu) * rstd * g1.y + b1.y);
  orow[i1 + 2] = f2bf((c.z - mu) * rstd * g1.z + b1.z);
  orow[i1 + 3] = f2bf((c.w - mu) * rstd * g1.w + b1.w);
}

// ---------------- MFMA GEMM: R13 + KS (k-subtiles per LDS stage) ----------------
// R13 all-1D config restored (250.4us proven best). ONLY change: KS template param.
// KS=2 (FF1 only): 64-wide K-step = half the vmcnt(0)+barrier drains (8 vs 16),
// 32 MFMA between barriers. LDS 48KB -> 3 blocks/CU (vs 6): trade occupancy for
// half the structural stalls. Sub-tiles computed k-ascending -> per-element
// accumulation order unchanged -> bit-identical output.
template <int EPI, int TM, int TN, int MINW, int KS>
__global__ __launch_bounds__(256, MINW) void gemm_kernel(
    const u16* __restrict__ A, const u16* __restrict__ Bt, int K,
    const float* __restrict__ resid, float* __restrict__ outf,
    u16* __restrict__ ob0, u16* __restrict__ ob1, u16* __restrict__ ob2) {
  constexpr int MR  = TM / 32;
  constexpr int NR  = TN / 32;
  constexpr int NAR = TM / 64;
  constexpr int NBR = TN / 64;
  __shared__ __align__(16) u16 As[2][KS][TM * 32];
  __shared__ __align__(16) u16 Bs[2][KS][TN * 32];
  int tid = threadIdx.x;
  int lane = tid & 63, wave = tid >> 6;
  int lane16 = lane & 15, quad = lane >> 4;
  int n1d = blockIdx.x;
  int m0 = (n1d & 63) * TM;
  int n0 = (n1d >> 6) * TN;
  int wm = (wave >> 1) * (TM / 2), wn = (wave & 1) * (TN / 2);

  floatx4 acc[MR][NR];
  #pragma unroll
  for (int i = 0; i < MR; i++)
    #pragma unroll
    for (int j = 0; j < NR; j++) acc[i][j] = (floatx4)(0.0f);

  const u16* agp[NAR]; const u16* bgp[NBR];
  #pragma unroll
  for (int i = 0; i < NAR; i++) {
    int s = i * 256 + tid;
    agp[i] = A + (size_t)(m0 + (s >> 2)) * K + (s & 3) * 8;
  }
  #pragma unroll
  for (int i = 0; i < NBR; i++) {
    int s = i * 256 + tid;
    bgp[i] = Bt + (size_t)(n0 + (s >> 2)) * K + (s & 3) * 8;
  }

  int nkS = K / (32 * KS);
  #pragma unroll
  for (int sub = 0; sub < KS; sub++) {
    int koff = sub * 32;
    #pragma unroll
    for (int i = 0; i < NAR; i++) glds16(agp[i] + koff, &As[0][sub][(i * 256 + wave * 64) * 8]);
    #pragma unroll
    for (int i = 0; i < NBR; i++) glds16(bgp[i] + koff, &Bs[0][sub][(i * 256 + wave * 64) * 8]);
  }

  for (int kt = 0; kt < nkS; kt++) {
    __syncthreads();
    int buf = kt & 1;
    if (kt + 1 < nkS) {
      #pragma unroll
      for (int sub = 0; sub < KS; sub++) {
        int koff = ((kt + 1) * KS + sub) * 32;
        #pragma unroll
        for (int i = 0; i < NAR; i++) glds16(agp[i] + koff, &As[buf ^ 1][sub][(i * 256 + wave * 64) * 8]);
        #pragma unroll
        for (int i = 0; i < NBR; i++) glds16(bgp[i] + koff, &Bs[buf ^ 1][sub][(i * 256 + wave * 64) * 8]);
      }
    }
    #pragma unroll
    for (int sub = 0; sub < KS; sub++) {
      short8 af[MR];
      #pragma unroll
      for (int i = 0; i < MR; i++)
        af[i] = *(const short8*)&As[buf][sub][(wm + i * 16 + lane16) * 32 + quad * 8];
      #pragma unroll
      for (int j = 0; j < NR; j++) {
        short8 bfj = *(const short8*)&Bs[buf][sub][(wn + j * 16 + lane16) * 32 + quad * 8];
        #pragma unroll
        for (int i = 0; i < MR; i++)
          acc[i][j] = __builtin_amdgcn_mfma_f32_16x16x32_bf16(af[i], bfj, acc[i][j], 0, 0, 0);
      }
    }
  }

  #pragma unroll
  for (int i = 0; i < MR; i++) {
    #pragma unroll
    for (int j = 0; j < NR; j++) {
      #pragma unroll
      for (int r = 0; r < 4; r++) {
        int m = m0 + wm + i * 16 + quad * 4 + r;
        int n = n0 + wn + j * 16 + lane16;
        float v = acc[i][j][r];
        if (EPI == 0) {
          int bb = m >> 11, t = m & 2047;
          int nn = n & 511, which = n >> 9;
          int h = nn >> 7, d = nn & 127;
          size_t base = (size_t)(bb * NH + h) * 262144;
          if (which == 0) {
            int t16 = t >> 4, l16 = t & 15, cc = d >> 5, qd = (d >> 3) & 3, e = d & 7;
            ob0[base + (size_t)((t16 * 16 + cc * 4 + qd) * 128 + l16 * 8 + e)] = f2bf(v * 0.12751743f);
          } else if (which == 1) {
            int kt2 = t >> 5, hf = (t >> 4) & 1, l16 = t & 15, cc = d >> 5, qd = (d >> 3) & 3, e = d & 7;
            ob1[base + (size_t)((kt2 * 8 + hf * 4 + cc) * 512 + qd * 128 + l16 * 8 + e)] = f2bf(v);
          } else {
            int kt2 = t >> 5, qv = (t >> 3) & 3, e = t & 7, j2 = d >> 4, l16 = d & 15;
            ob2[base + (size_t)((kt2 * 8 + j2) * 512 + qv * 128 + l16 * 8 + e)] = f2bf(v);
          }
        } else if (EPI == 1) {
          size_t idx = (size_t)m * CMOD + n;
          outf[idx] = v + resid[idx];
        } else if (EPI == 2) {
          float ge = 0.5f * v * (1.0f + erff(v * 0.70710678118654752f));
          ob0[(size_t)m * DFF + n] = f2bf(ge);
        } else {
          size_t idx = (size_t)m * CMOD + n;
          outf[idx] = v + resid[idx];
        }
      }
    }
  }
}

// ---------------- flash attention: R12 (frozen) ----------------
__global__ __launch_bounds__(128) void attn_kernel(const u16* __restrict__ qb,
                                                   const u16* __restrict__ kb,
                                                   const u16* __restrict__ vtb,
                                                   u16* __restrict__ po,
                                                   float* __restrict__ pl) {
  int tid = threadIdx.x, wave = tid >> 6, lane = tid & 63;
  int lane16 = lane & 15, quad = lane >> 4;
  int n1d = blockIdx.x;
  int bh = n1d & 15;
  int idx = 143 - (n1d >> 4);   // heavy (large qt) chunks dispatch first
  int g = 1;
  #pragma unroll
  for (int t = 2; t <= 8; t++) if (idx >= 2 * t * (t - 1)) g = t;
  int rem = idx - 2 * g * (g - 1);
  int qi = rem / g;
  int c  = rem - qi * g;
  int qt = ((g - 1) << 2) + qi;

  int q0w = qt * 64 + wave * 32;   // 32 rows per wave
  const u16* Qb = qb  + (size_t)bh * 262144;
  const u16* Kb = kb  + (size_t)bh * 262144;
  const u16* Vb = vtb + (size_t)bh * 262144;

  short8 aqA[4], aqB[4];
  {
    int t16 = q0w >> 4;
    #pragma unroll
    for (int cc = 0; cc < 4; cc++) {
      aqA[cc] = *(const short8*)&Qb[(size_t)((t16 * 16 + cc * 4 + quad) * 128 + lane16 * 8)];
      aqB[cc] = *(const short8*)&Qb[(size_t)(((t16 + 1) * 16 + cc * 4 + quad) * 128 + lane16 * 8)];
    }
  }

  int ktw   = (q0w >> 5) + 1;
  int ktblk = qt * 2 + 2;
  int kt0   = c * 8;
  int kend  = min(min(kt0 + 8, ktblk), ktw);

  floatx4 oA[8], oB[8];
  #pragma unroll
  for (int j = 0; j < 8; j++) { oA[j] = (floatx4)(0.0f); oB[j] = (floatx4)(0.0f); }
  floatx4 olA = (floatx4)(0.0f), olB = (floatx4)(0.0f);

  short8 ones;
  #pragma unroll
  for (int e = 0; e < 8; e++) ones[e] = (short)0x3F80;

  int addrA = (lane16 + ((quad & 1) << 5)) << 2;
  int addrB = addrA + 64;
  int q_gA = q0w + lane16;
  int q_gB = q0w + 16 + lane16;

#define ATTN_TAIL(S0, S1, O_, OL_, QG, KT)                                                          \
  {                                                                                                 \
    int k0b = (KT) * 32 + quad * 4;                                                                 \
    _Pragma("unroll")                                                                               \
    for (int r = 0; r < 4; r++) {                                                                   \
      float p0 = exp2a(S0[r]);                                                                      \
      float p1 = exp2a(S1[r]);                                                                      \
      if (k0b + r > (QG)) p0 = 0.0f;                                                                \
      if (k0b + r + 16 > (QG)) p1 = 0.0f;                                                           \
      S0[r] = p0; S1[r] = p1;                                                                       \
    }                                                                                               \
    uint32_t x0 = __builtin_amdgcn_perm(__float_as_uint(S0[1]), __float_as_uint(S0[0]), 0x07060302u); \
    uint32_t x1 = __builtin_amdgcn_perm(__float_as_uint(S0[3]), __float_as_uint(S0[2]), 0x07060302u); \
    uint32_t y0 = __builtin_amdgcn_perm(__float_as_uint(S1[1]), __float_as_uint(S1[0]), 0x07060302u); \
    uint32_t y1 = __builtin_amdgcn_perm(__float_as_uint(S1[3]), __float_as_uint(S1[2]), 0x07060302u); \
    int pAx0 = __builtin_amdgcn_ds_bpermute(addrA, (int)x0);                                        \
    int pAx1 = __builtin_amdgcn_ds_bpermute(addrA, (int)x1);                                        \
    int pBx0 = __builtin_amdgcn_ds_bpermute(addrB, (int)x0);                                        \
    int pBx1 = __builtin_amdgcn_ds_bpermute(addrB, (int)x1);                                        \
    int pAy0 = __builtin_amdgcn_ds_bpermute(addrA, (int)y0);                                        \
    int pAy1 = __builtin_amdgcn_ds_bpermute(addrA, (int)y1);                                        \
    int pBy0 = __builtin_amdgcn_ds_bpermute(addrB, (int)y0);                                        \
    int pBy1 = __builtin_amdgcn_ds_bpermute(addrB, (int)y1);                                        \
    union { uint32_t u[4]; short8 s; } pf;                                                          \
    bool hi = quad >= 2;                                                                            \
    pf.u[0] = (uint32_t)(hi ? pAy0 : pAx0);                                                         \
    pf.u[1] = (uint32_t)(hi ? pAy1 : pAx1);                                                         \
    pf.u[2] = (uint32_t)(hi ? pBy0 : pBx0);                                                         \
    pf.u[3] = (uint32_t)(hi ? pBy1 : pBx1);                                                         \
    _Pragma("unroll")                                                                               \
    for (int j = 0; j < 8; j++)                                                                     \
      O_[j] = __builtin_amdgcn_mfma_f32_16x16x32_bf16(pf.s, vfr[j], O_[j], 0, 0, 0);                \
    OL_ = __builtin_amdgcn_mfma_f32_16x16x32_bf16(pf.s, ones, OL_, 0, 0, 0);                        \
  }

  for (int kt = kt0; kt < kend; kt++) {
    const u16* kp = Kb + (size_t)kt * 4096 + lane * 8;
    const u16* vp = Vb + (size_t)kt * 4096 + lane * 8;
    short8 k0f[4], k1f[4];
    #pragma unroll
    for (int cc = 0; cc < 4; cc++) {
      k0f[cc] = *(const short8*)&kp[cc * 512];
      k1f[cc] = *(const short8*)&kp[(4 + cc) * 512];
    }

    floatx4 sA0 = (floatx4)(0.0f), sA1 = (floatx4)(0.0f);
    floatx4 sB0 = (floatx4)(0.0f), sB1 = (floatx4)(0.0f);
    #pragma unroll
    for (int cc = 0; cc < 4; cc++) {
      sA0 = __builtin_amdgcn_mfma_f32_16x16x32_bf16(k0f[cc], aqA[cc], sA0, 0, 0, 0);
      sA1 = __builtin_amdgcn_mfma_f32_16x16x32_bf16(k1f[cc], aqA[cc], sA1, 0, 0, 0);
      sB0 = __builtin_amdgcn_mfma_f32_16x16x32_bf16(k0f[cc], aqB[cc], sB0, 0, 0, 0);
      sB1 = __builtin_amdgcn_mfma_f32_16x16x32_bf16(k1f[cc], aqB[cc], sB1, 0, 0, 0);
    }

    short8 vfr[8];
    #pragma unroll
    for (int j = 0; j < 8; j++)
      vfr[j] = *(const short8*)&vp[j * 512];

    ATTN_TAIL(sA0, sA1, oA, olA, q_gA, kt);
    ATTN_TAIL(sB0, sB1, oB, olB, q_gB, kt);
  }
#undef ATTN_TAIL

  int slot = bh * 144 + 2 * g * (g - 1) + qi * g + c;
  u16* pob = po + (size_t)slot * 8192;
  #pragma unroll
  for (int r = 0; r < 4; r++) {
    int qrA = wave * 32 + quad * 4 + r;
    int qrB = qrA + 16;
    #pragma unroll
    for (int j = 0; j < 8; j++) {
      pob[qrA * 128 + j * 16 + lane16] = f2bf(oA[j][r]);
      pob[qrB * 128 + j * 16 + lane16] = f2bf(oB[j][r]);
    }
    if (lane16 == 0) {
      pl[slot * 64 + qrA] = olA[r];
      pl[slot * 64 + qrB] = olB[r];
    }
  }
}

// ---------------- reduce: R11 slot mapping (frozen) ----------------
__global__ __launch_bounds__(256) void reduce_kernel(const u16* __restrict__ po,
                                                     const float* __restrict__ pl,
                                                     u16* __restrict__ attn) {
  int bh = blockIdx.x >> 5, qt = blockIdx.x & 31;
  int tid = threadIdx.x;
  int g = (qt >> 2) + 1;
  int slot0 = bh * 144 + 2 * g * (g - 1) + (qt & 3) * g;
  int qrow = tid >> 2;
  int d0 = (tid & 3) * 32;
  float acc[32];
  #pragma unroll
  for (int i = 0; i < 32; i++) acc[i] = 0.0f;
  float l = 0.0f;
  for (int c = 0; c < g; c++) {
    int slot = slot0 + c;
    l += pl[slot * 64 + qrow];
    const short8* p = (const short8*)(po + (size_t)slot * 8192 + qrow * 128 + d0);
    #pragma unroll
    for (int v = 0; v < 4; v++) {
      short8 pk = p[v];
      #pragma unroll
      for (int e = 0; e < 8; e++) acc[v * 8 + e] += bf2f((u16)pk[e]);
    }
  }
  float inv = rcpa(l);
  int b = bh >> 2, h = bh & 3, t = qt * 64 + qrow;
  u16* orow = attn + ((size_t)(b * TSEQ + t)) * CMOD + h * HD + d0;
  #pragma unroll
  for (int v = 0; v < 4; v++) {
    short8 ov;
    #pragma unroll
    for (int e = 0; e < 8; e++) ov[e] = (short)f2bf(acc[v * 8 + e] * inv);
    *(short8*)(orow + v * 8) = ov;
  }
}

extern "C" void kernel_launch(void* const* d_in, const int* in_sizes, int n_in,
                              void* d_out, int out_size, void* d_ws, size_t ws_size,
                              hipStream_t stream) {
  const float* x     = (const float*)d_in[0];
  const float* ln1g  = (const float*)d_in[1];
  const float* ln1b  = (const float*)d_in[2];
  const float* wqkv  = (const float*)d_in[3];
  const float* wproj = (const float*)d_in[4];
  const float* ln2g  = (const float*)d_in[5];
  const float* ln2b  = (const float*)d_in[6];
  const float* wff1  = (const float*)d_in[7];
  const float* wff2  = (const float*)d_in[8];
  float* out = (float*)d_out;
  char* ws = (char*)d_ws;

  u16* wt_qkv  = (u16*)(ws);
  u16* wt_proj = (u16*)(ws + 1572864);
  u16* wt_ff1  = (u16*)(ws + 2097152);
  u16* wt_ff2  = (u16*)(ws + 4194304);
  u16* ln_buf  = (u16*)(ws + 6291456);
  u16* q_buf   = (u16*)(ws + 14680064);
  u16* k_buf   = (u16*)(ws + 23068672);
  u16* vt_buf  = (u16*)(ws + 31457280);
  u16* attn    = (u16*)(ws + 39845888);
  float* x2    = (float*)(ws + 48234496);
  u16* h1      = (u16*)(ws + 65011712);
  u16* po      = (u16*)(ws + 48234496);
  float* pl    = (float*)(ws + 85983232);

  dim3 blk(256);
  prep_kernel<<<dim3(5120), blk, 0, stream>>>(x, ln1g, ln1b, wqkv, wproj, wff1, wff2,
                                              ln_buf, wt_qkv, wt_proj, wt_ff1, wt_ff2);

  // QKV: R13 config (1D grid, KS=1)
  gemm_kernel<0, 128, 64, 6, 1><<<dim3((CQKV / 64) * 64), blk, 0, stream>>>(
      ln_buf, wt_qkv, CMOD, nullptr, nullptr, q_buf, k_buf, vt_buf);

  // attn: grid 2304 x 128 threads (2 waves x 32 q-rows), XCD swizzle (bh = n & 15)
  attn_kernel<<<dim3(2304), dim3(128), 0, stream>>>(q_buf, k_buf, vt_buf, po, pl);

  reduce_kernel<<<dim3(512), blk, 0, stream>>>(po, pl, attn);

  // proj: R13 config (1D grid, KS=1)
  gemm_kernel<1, 128, 64, 4, 1><<<dim3((CMOD / 64) * 64), blk, 0, stream>>>(
      attn, wt_proj, CMOD, x, x2, nullptr, nullptr, nullptr);

  ln_kernel<<<dim3(BT / 4), blk, 0, stream>>>(x2, ln2g, ln2b, ln_buf);

  // FF1: KS=2 (64-wide K-step, 8 barriers instead of 16; LDS 48KB -> 3 blk/CU)
  gemm_kernel<2, 128, 64, 3, 2><<<dim3((DFF / 64) * 64), blk, 0, stream>>>(
      ln_buf, wt_ff1, CMOD, nullptr, nullptr, h1, nullptr, nullptr);

  // FF2: R13 config (1D grid, KS=1)
  gemm_kernel<3, 128, 64, 4, 1><<<dim3((CMOD / 64) * 64), blk, 0, stream>>>(
      h1, wt_ff2, DFF, x2, out, nullptr, nullptr, nullptr);
}

// Round 17
// 249.503 us; speedup vs baseline: 1.0199x; 1.0048x over previous
//
#include <hip/hip_runtime.h>
#include <cstdint>

typedef unsigned short u16;
typedef __attribute__((ext_vector_type(8))) short short8;
typedef __attribute__((ext_vector_type(4))) float floatx4;

#define BT    8192
#define TSEQ  2048
#define NBAT  4
#define CMOD  512
#define NH    4
#define HD    128
#define DFF   2048
#define CQKV  1536

__device__ __forceinline__ u16 f2bf(float f) {
  union { float f; uint32_t u; } v; v.f = f;
  uint32_t r = v.u + 0x7FFFu + ((v.u >> 16) & 1u);
  return (u16)(r >> 16);
}
__device__ __forceinline__ float bf2f(u16 u) {
  union { uint32_t u; float f; } v; v.u = ((uint32_t)u) << 16; return v.f;
}
__device__ __forceinline__ float exp2a(float x) {
  float r; asm("v_exp_f32 %0, %1" : "=v"(r) : "v"(x)); return r;
}
__device__ __forceinline__ float rcpa(float x) {
  float r; asm("v_rcp_f32 %0, %1" : "=v"(r) : "v"(x)); return r;
}

typedef __attribute__((address_space(1))) const unsigned int ga_u32;
typedef __attribute__((address_space(3))) unsigned int ls_u32;
__device__ __forceinline__ void glds16(const u16* g, u16* l) {
  __builtin_amdgcn_global_load_lds((ga_u32*)g, (ls_u32*)l, 16, 0, 0);
}

// ---------------- weight transpose body (unchanged math) ----------------
__device__ __forceinline__ void tcast_body(const float* __restrict__ W, u16* __restrict__ Wt,
                                           int K, int N, int bx, int by, int tid,
                                           float (*tile)[33]) {
  int n0 = bx * 32, k0 = by * 32;
  int tx = tid & 31, ty = tid >> 5;
  #pragma unroll
  for (int r = 0; r < 32; r += 8)
    tile[r + ty][tx] = W[(size_t)(k0 + r + ty) * N + n0 + tx];
  __syncthreads();
  #pragma unroll
  for (int r = 0; r < 32; r += 8)
    Wt[(size_t)(n0 + r + ty) * K + k0 + tx] = f2bf(tile[tx][r + ty]);
}

// ---------------- prep: ONLY wqkv transpose + LN1 (critical-path trim) ----------------
// wproj/wff1/wff2 transposes moved into the reduce launch (not needed until
// proj/FF1/FF2); prep 5120 -> 2816 blocks so QKV starts earlier. Same stores.
__global__ __launch_bounds__(256) void prep_kernel(
    const float* __restrict__ x, const float* __restrict__ g, const float* __restrict__ b,
    const float* __restrict__ wqkv, u16* __restrict__ ln_out, u16* __restrict__ wqkvT) {
  __shared__ float tile[32][33];
  int bid = blockIdx.x, tid = threadIdx.x;
  if (bid < 768) {
    tcast_body(wqkv, wqkvT, CMOD, CQKV, bid % 48, bid / 48, tid, tile);
  } else {
    int row = (bid - 768) * 4 + (tid >> 6);
    int lane = tid & 63;
    const float4* xr = (const float4*)(x + (size_t)row * CMOD);
    float4 a = xr[lane], c = xr[lane + 64];
    float s = a.x + a.y + a.z + a.w + c.x + c.y + c.z + c.w;
    float q = a.x*a.x + a.y*a.y + a.z*a.z + a.w*a.w
            + c.x*c.x + c.y*c.y + c.z*c.z + c.w*c.w;
    #pragma unroll
    for (int o = 32; o; o >>= 1) { s += __shfl_xor(s, o); q += __shfl_xor(q, o); }
    float mu = s * (1.0f / CMOD);
    float rstd = rsqrtf(q * (1.0f / CMOD) - mu * mu + 1e-5f);
    const float4* gr = (const float4*)g;
    const float4* br = (const float4*)b;
    float4 g0 = gr[lane], g1 = gr[lane + 64], b0 = br[lane], b1 = br[lane + 64];
    u16* orow = ln_out + (size_t)row * CMOD;
    int i0 = lane * 4, i1 = (lane + 64) * 4;
    orow[i0 + 0] = f2bf((a.x - mu) * rstd * g0.x + b0.x);
    orow[i0 + 1] = f2bf((a.y - mu) * rstd * g0.y + b0.y);
    orow[i0 + 2] = f2bf((a.z - mu) * rstd * g0.z + b0.z);
    orow[i0 + 3] = f2bf((a.w - mu) * rstd * g0.w + b0.w);
    orow[i1 + 0] = f2bf((c.x - mu) * rstd * g1.x + b1.x);
    orow[i1 + 1] = f2bf((c.y - mu) * rstd * g1.y + b1.y);
    orow[i1 + 2] = f2bf((c.z - mu) * rstd * g1.z + b1.z);
    orow[i1 + 3] = f2bf((c.w - mu) * rstd * g1.w + b1.w);
  }
}

// ---------------- layernorm (standalone, for LN2; frozen) ----------------
__global__ __launch_bounds__(256) void ln_kernel(const float* __restrict__ x,
                                                 const float* __restrict__ g,
                                                 const float* __restrict__ b,
                                                 u16* __restrict__ out) {
  int row = blockIdx.x * 4 + (threadIdx.x >> 6);
  int lane = threadIdx.x & 63;
  const float4* xr = (const float4*)(x + (size_t)row * CMOD);
  float4 a = xr[lane], c = xr[lane + 64];
  float s = a.x + a.y + a.z + a.w + c.x + c.y + c.z + c.w;
  float q = a.x*a.x + a.y*a.y + a.z*a.z + a.w*a.w
          + c.x*c.x + c.y*c.y + c.z*c.z + c.w*c.w;
  #pragma unroll
  for (int o = 32; o; o >>= 1) { s += __shfl_xor(s, o); q += __shfl_xor(q, o); }
  float mu = s * (1.0f / CMOD);
  float rstd = rsqrtf(q * (1.0f / CMOD) - mu * mu + 1e-5f);
  const float4* gr = (const float4*)g;
  const float4* br = (const float4*)b;
  float4 g0 = gr[lane], g1 = gr[lane + 64], b0 = br[lane], b1 = br[lane + 64];
  u16* orow = out + (size_t)row * CMOD;
  int i0 = lane * 4, i1 = (lane + 64) * 4;
  orow[i0 + 0] = f2bf((a.x - mu) * rstd * g0.x + b0.x);
  orow[i0 + 1] = f2bf((a.y - mu) * rstd * g0.y + b0.y);
  orow[i0 + 2] = f2bf((a.z - mu) * rstd * g0.z + b0.z);
  orow[i0 + 3] = f2bf((a.w - mu) * rstd * g0.w + b0.w);
  orow[i1 + 0] = f2bf((c.x - mu) * rstd * g1.x + b1.x);
  orow[i1 + 1] = f2bf((c.y - mu) * rstd * g1.y + b1.y);
  orow[i1 + 2] = f2bf((c.z - mu) * rstd * g1.z + b1.z);
  orow[i1 + 3] = f2bf((c.w - mu) * rstd * g1.w + b1.w);
}

// ---------------- MFMA GEMM: R13 exact (1D XCD grid, KS reverted) ----------------
template <int EPI, int TM, int TN, int MINW>
__global__ __launch_bounds__(256, MINW) void gemm_kernel(
    const u16* __restrict__ A, const u16* __restrict__ Bt, int K,
    const float* __restrict__ resid, float* __restrict__ outf,
    u16* __restrict__ ob0, u16* __restrict__ ob1, u16* __restrict__ ob2) {
  constexpr int MR  = TM / 32;
  constexpr int NR  = TN / 32;
  constexpr int NAR = TM / 64;
  constexpr int NBR = TN / 64;
  __shared__ __align__(16) u16 As[2][TM * 32];
  __shared__ __align__(16) u16 Bs[2][TN * 32];
  int tid = threadIdx.x;
  int lane = tid & 63, wave = tid >> 6;
  int lane16 = lane & 15, quad = lane >> 4;
  int n1d = blockIdx.x;
  int m0 = (n1d & 63) * TM;
  int n0 = (n1d >> 6) * TN;
  int wm = (wave >> 1) * (TM / 2), wn = (wave & 1) * (TN / 2);

  floatx4 acc[MR][NR];
  #pragma unroll
  for (int i = 0; i < MR; i++)
    #pragma unroll
    for (int j = 0; j < NR; j++) acc[i][j] = (floatx4)(0.0f);

  const u16* agp[NAR]; u16* alp[NAR][2];
  const u16* bgp[NBR]; u16* blp[NBR][2];
  #pragma unroll
  for (int i = 0; i < NAR; i++) {
    int s = i * 256 + tid;
    agp[i] = A + (size_t)(m0 + (s >> 2)) * K + (s & 3) * 8;
    alp[i][0] = &As[0][(i * 256 + wave * 64) * 8];
    alp[i][1] = &As[1][(i * 256 + wave * 64) * 8];
  }
  #pragma unroll
  for (int i = 0; i < NBR; i++) {
    int s = i * 256 + tid;
    bgp[i] = Bt + (size_t)(n0 + (s >> 2)) * K + (s & 3) * 8;
    blp[i][0] = &Bs[0][(i * 256 + wave * 64) * 8];
    blp[i][1] = &Bs[1][(i * 256 + wave * 64) * 8];
  }

  int nk = K >> 5;
  #pragma unroll
  for (int i = 0; i < NAR; i++) glds16(agp[i], alp[i][0]);
  #pragma unroll
  for (int i = 0; i < NBR; i++) glds16(bgp[i], blp[i][0]);

  for (int kt = 0; kt < nk; kt++) {
    __syncthreads();
    int buf = kt & 1;
    if (kt + 1 < nk) {
      int k1 = (kt + 1) * 32;
      #pragma unroll
      for (int i = 0; i < NAR; i++) glds16(agp[i] + k1, alp[i][buf ^ 1]);
      #pragma unroll
      for (int i = 0; i < NBR; i++) glds16(bgp[i] + k1, blp[i][buf ^ 1]);
    }
    short8 af[MR];
    #pragma unroll
    for (int i = 0; i < MR; i++)
      af[i] = *(const short8*)&As[buf][(wm + i * 16 + lane16) * 32 + quad * 8];
    #pragma unroll
    for (int j = 0; j < NR; j++) {
      short8 bfj = *(const short8*)&Bs[buf][(wn + j * 16 + lane16) * 32 + quad * 8];
      #pragma unroll
      for (int i = 0; i < MR; i++)
        acc[i][j] = __builtin_amdgcn_mfma_f32_16x16x32_bf16(af[i], bfj, acc[i][j], 0, 0, 0);
    }
  }

  #pragma unroll
  for (int i = 0; i < MR; i++) {
    #pragma unroll
    for (int j = 0; j < NR; j++) {
      #pragma unroll
      for (int r = 0; r < 4; r++) {
        int m = m0 + wm + i * 16 + quad * 4 + r;
        int n = n0 + wn + j * 16 + lane16;
        float v = acc[i][j][r];
        if (EPI == 0) {
          int bb = m >> 11, t = m & 2047;
          int nn = n & 511, which = n >> 9;
          int h = nn >> 7, d = nn & 127;
          size_t base = (size_t)(bb * NH + h) * 262144;
          if (which == 0) {
            int t16 = t >> 4, l16 = t & 15, cc = d >> 5, qd = (d >> 3) & 3, e = d & 7;
            ob0[base + (size_t)((t16 * 16 + cc * 4 + qd) * 128 + l16 * 8 + e)] = f2bf(v * 0.12751743f);
          } else if (which == 1) {
            int kt2 = t >> 5, hf = (t >> 4) & 1, l16 = t & 15, cc = d >> 5, qd = (d >> 3) & 3, e = d & 7;
            ob1[base + (size_t)((kt2 * 8 + hf * 4 + cc) * 512 + qd * 128 + l16 * 8 + e)] = f2bf(v);
          } else {
            int kt2 = t >> 5, qv = (t >> 3) & 3, e = t & 7, j2 = d >> 4, l16 = d & 15;
            ob2[base + (size_t)((kt2 * 8 + j2) * 512 + qv * 128 + l16 * 8 + e)] = f2bf(v);
          }
        } else if (EPI == 1) {
          size_t idx = (size_t)m * CMOD + n;
          outf[idx] = v + resid[idx];
        } else if (EPI == 2) {
          float ge = 0.5f * v * (1.0f + erff(v * 0.70710678118654752f));
          ob0[(size_t)m * DFF + n] = f2bf(ge);
        } else {
          size_t idx = (size_t)m * CMOD + n;
          outf[idx] = v + resid[idx];
        }
      }
    }
  }
}

// ---------------- flash attention: R12 (frozen) ----------------
__global__ __launch_bounds__(128) void attn_kernel(const u16* __restrict__ qb,
                                                   const u16* __restrict__ kb,
                                                   const u16* __restrict__ vtb,
                                                   u16* __restrict__ po,
                                                   float* __restrict__ pl) {
  int tid = threadIdx.x, wave = tid >> 6, lane = tid & 63;
  int lane16 = lane & 15, quad = lane >> 4;
  int n1d = blockIdx.x;
  int bh = n1d & 15;
  int idx = 143 - (n1d >> 4);   // heavy (large qt) chunks dispatch first
  int g = 1;
  #pragma unroll
  for (int t = 2; t <= 8; t++) if (idx >= 2 * t * (t - 1)) g = t;
  int rem = idx - 2 * g * (g - 1);
  int qi = rem / g;
  int c  = rem - qi * g;
  int qt = ((g - 1) << 2) + qi;

  int q0w = qt * 64 + wave * 32;   // 32 rows per wave
  const u16* Qb = qb  + (size_t)bh * 262144;
  const u16* Kb = kb  + (size_t)bh * 262144;
  const u16* Vb = vtb + (size_t)bh * 262144;

  short8 aqA[4], aqB[4];
  {
    int t16 = q0w >> 4;
    #pragma unroll
    for (int cc = 0; cc < 4; cc++) {
      aqA[cc] = *(const short8*)&Qb[(size_t)((t16 * 16 + cc * 4 + quad) * 128 + lane16 * 8)];
      aqB[cc] = *(const short8*)&Qb[(size_t)(((t16 + 1) * 16 + cc * 4 + quad) * 128 + lane16 * 8)];
    }
  }

  int ktw   = (q0w >> 5) + 1;
  int ktblk = qt * 2 + 2;
  int kt0   = c * 8;
  int kend  = min(min(kt0 + 8, ktblk), ktw);

  floatx4 oA[8], oB[8];
  #pragma unroll
  for (int j = 0; j < 8; j++) { oA[j] = (floatx4)(0.0f); oB[j] = (floatx4)(0.0f); }
  floatx4 olA = (floatx4)(0.0f), olB = (floatx4)(0.0f);

  short8 ones;
  #pragma unroll
  for (int e = 0; e < 8; e++) ones[e] = (short)0x3F80;

  int addrA = (lane16 + ((quad & 1) << 5)) << 2;
  int addrB = addrA + 64;
  int q_gA = q0w + lane16;
  int q_gB = q0w + 16 + lane16;

#define ATTN_TAIL(S0, S1, O_, OL_, QG, KT)                                                          \
  {                                                                                                 \
    int k0b = (KT) * 32 + quad * 4;                                                                 \
    _Pragma("unroll")                                                                               \
    for (int r = 0; r < 4; r++) {                                                                   \
      float p0 = exp2a(S0[r]);                                                                      \
      float p1 = exp2a(S1[r]);                                                                      \
      if (k0b + r > (QG)) p0 = 0.0f;                                                                \
      if (k0b + r + 16 > (QG)) p1 = 0.0f;                                                           \
      S0[r] = p0; S1[r] = p1;                                                                       \
    }                                                                                               \
    uint32_t x0 = __builtin_amdgcn_perm(__float_as_uint(S0[1]), __float_as_uint(S0[0]), 0x07060302u); \
    uint32_t x1 = __builtin_amdgcn_perm(__float_as_uint(S0[3]), __float_as_uint(S0[2]), 0x07060302u); \
    uint32_t y0 = __builtin_amdgcn_perm(__float_as_uint(S1[1]), __float_as_uint(S1[0]), 0x07060302u); \
    uint32_t y1 = __builtin_amdgcn_perm(__float_as_uint(S1[3]), __float_as_uint(S1[2]), 0x07060302u); \
    int pAx0 = __builtin_amdgcn_ds_bpermute(addrA, (int)x0);                                        \
    int pAx1 = __builtin_amdgcn_ds_bpermute(addrA, (int)x1);                                        \
    int pBx0 = __builtin_amdgcn_ds_bpermute(addrB, (int)x0);                                        \
    int pBx1 = __builtin_amdgcn_ds_bpermute(addrB, (int)x1);                                        \
    int pAy0 = __builtin_amdgcn_ds_bpermute(addrA, (int)y0);                                        \
    int pAy1 = __builtin_amdgcn_ds_bpermute(addrA, (int)y1);                                        \
    int pBy0 = __builtin_amdgcn_ds_bpermute(addrB, (int)y0);                                        \
    int pBy1 = __builtin_amdgcn_ds_bpermute(addrB, (int)y1);                                        \
    union { uint32_t u[4]; short8 s; } pf;                                                          \
    bool hi = quad >= 2;                                                                            \
    pf.u[0] = (uint32_t)(hi ? pAy0 : pAx0);                                                         \
    pf.u[1] = (uint32_t)(hi ? pAy1 : pAx1);                                                         \
    pf.u[2] = (uint32_t)(hi ? pBy0 : pBx0);                                                         \
    pf.u[3] = (uint32_t)(hi ? pBy1 : pBx1);                                                         \
    _Pragma("unroll")                                                                               \
    for (int j = 0; j < 8; j++)                                                                     \
      O_[j] = __builtin_amdgcn_mfma_f32_16x16x32_bf16(pf.s, vfr[j], O_[j], 0, 0, 0);                \
    OL_ = __builtin_amdgcn_mfma_f32_16x16x32_bf16(pf.s, ones, OL_, 0, 0, 0);                        \
  }

  for (int kt = kt0; kt < kend; kt++) {
    const u16* kp = Kb + (size_t)kt * 4096 + lane * 8;
    const u16* vp = Vb + (size_t)kt * 4096 + lane * 8;
    short8 k0f[4], k1f[4];
    #pragma unroll
    for (int cc = 0; cc < 4; cc++) {
      k0f[cc] = *(const short8*)&kp[cc * 512];
      k1f[cc] = *(const short8*)&kp[(4 + cc) * 512];
    }

    floatx4 sA0 = (floatx4)(0.0f), sA1 = (floatx4)(0.0f);
    floatx4 sB0 = (floatx4)(0.0f), sB1 = (floatx4)(0.0f);
    #pragma unroll
    for (int cc = 0; cc < 4; cc++) {
      sA0 = __builtin_amdgcn_mfma_f32_16x16x32_bf16(k0f[cc], aqA[cc], sA0, 0, 0, 0);
      sA1 = __builtin_amdgcn_mfma_f32_16x16x32_bf16(k1f[cc], aqA[cc], sA1, 0, 0, 0);
      sB0 = __builtin_amdgcn_mfma_f32_16x16x32_bf16(k0f[cc], aqB[cc], sB0, 0, 0, 0);
      sB1 = __builtin_amdgcn_mfma_f32_16x16x32_bf16(k1f[cc], aqB[cc], sB1, 0, 0, 0);
    }

    short8 vfr[8];
    #pragma unroll
    for (int j = 0; j < 8; j++)
      vfr[j] = *(const short8*)&vp[j * 512];

    ATTN_TAIL(sA0, sA1, oA, olA, q_gA, kt);
    ATTN_TAIL(sB0, sB1, oB, olB, q_gB, kt);
  }
#undef ATTN_TAIL

  int slot = bh * 144 + 2 * g * (g - 1) + qi * g + c;
  u16* pob = po + (size_t)slot * 8192;
  #pragma unroll
  for (int r = 0; r < 4; r++) {
    int qrA = wave * 32 + quad * 4 + r;
    int qrB = qrA + 16;
    #pragma unroll
    for (int j = 0; j < 8; j++) {
      pob[qrA * 128 + j * 16 + lane16] = f2bf(oA[j][r]);
      pob[qrB * 128 + j * 16 + lane16] = f2bf(oB[j][r]);
    }
    if (lane16 == 0) {
      pl[slot * 64 + qrA] = olA[r];
      pl[slot * 64 + qrB] = olB[r];
    }
  }
}

// ---------------- reduce + late weight transposes (wproj/wff1/wff2) ----------------
// bid<512: R11 reduction (unchanged). bid>=512: the three transposes moved out of
// prep — they overlap reduce's latency-bound blocks and finish before proj/FF1/FF2.
__global__ __launch_bounds__(256) void reduce_kernel(const u16* __restrict__ po,
                                                     const float* __restrict__ pl,
                                                     u16* __restrict__ attn,
                                                     const float* __restrict__ wproj,
                                                     const float* __restrict__ wff1,
                                                     const float* __restrict__ wff2,
                                                     u16* __restrict__ wprojT,
                                                     u16* __restrict__ wff1T,
                                                     u16* __restrict__ wff2T) {
  __shared__ float tile[32][33];
  int bid = blockIdx.x, tid = threadIdx.x;
  if (bid >= 512) {
    if (bid < 768) {
      int id = bid - 512; tcast_body(wproj, wprojT, CMOD, CMOD, id % 16, id / 16, tid, tile);
    } else if (bid < 1792) {
      int id = bid - 768; tcast_body(wff1, wff1T, CMOD, DFF, id % 64, id / 64, tid, tile);
    } else {
      int id = bid - 1792; tcast_body(wff2, wff2T, DFF, CMOD, id % 16, id / 16, tid, tile);
    }
    return;
  }
  int bh = bid >> 5, qt = bid & 31;
  int g = (qt >> 2) + 1;
  int slot0 = bh * 144 + 2 * g * (g - 1) + (qt & 3) * g;
  int qrow = tid >> 2;
  int d0 = (tid & 3) * 32;
  float acc[32];
  #pragma unroll
  for (int i = 0; i < 32; i++) acc[i] = 0.0f;
  float l = 0.0f;
  for (int c = 0; c < g; c++) {
    int slot = slot0 + c;
    l += pl[slot * 64 + qrow];
    const short8* p = (const short8*)(po + (size_t)slot * 8192 + qrow * 128 + d0);
    #pragma unroll
    for (int v = 0; v < 4; v++) {
      short8 pk = p[v];
      #pragma unroll
      for (int e = 0; e < 8; e++) acc[v * 8 + e] += bf2f((u16)pk[e]);
    }
  }
  float inv = rcpa(l);
  int b = bh >> 2, h = bh & 3, t = qt * 64 + qrow;
  u16* orow = attn + ((size_t)(b * TSEQ + t)) * CMOD + h * HD + d0;
  #pragma unroll
  for (int v = 0; v < 4; v++) {
    short8 ov;
    #pragma unroll
    for (int e = 0; e < 8; e++) ov[e] = (short)f2bf(acc[v * 8 + e] * inv);
    *(short8*)(orow + v * 8) = ov;
  }
}

extern "C" void kernel_launch(void* const* d_in, const int* in_sizes, int n_in,
                              void* d_out, int out_size, void* d_ws, size_t ws_size,
                              hipStream_t stream) {
  const float* x     = (const float*)d_in[0];
  const float* ln1g  = (const float*)d_in[1];
  const float* ln1b  = (const float*)d_in[2];
  const float* wqkv  = (const float*)d_in[3];
  const float* wproj = (const float*)d_in[4];
  const float* ln2g  = (const float*)d_in[5];
  const float* ln2b  = (const float*)d_in[6];
  const float* wff1  = (const float*)d_in[7];
  const float* wff2  = (const float*)d_in[8];
  float* out = (float*)d_out;
  char* ws = (char*)d_ws;

  u16* wt_qkv  = (u16*)(ws);
  u16* wt_proj = (u16*)(ws + 1572864);
  u16* wt_ff1  = (u16*)(ws + 2097152);
  u16* wt_ff2  = (u16*)(ws + 4194304);
  u16* ln_buf  = (u16*)(ws + 6291456);
  u16* q_buf   = (u16*)(ws + 14680064);
  u16* k_buf   = (u16*)(ws + 23068672);
  u16* vt_buf  = (u16*)(ws + 31457280);
  u16* attn    = (u16*)(ws + 39845888);
  float* x2    = (float*)(ws + 48234496);
  u16* h1      = (u16*)(ws + 65011712);
  u16* po      = (u16*)(ws + 48234496);
  float* pl    = (float*)(ws + 85983232);

  dim3 blk(256);
  // prep: wqkv transpose + LN1 only (768 + 2048 = 2816 blocks)
  prep_kernel<<<dim3(2816), blk, 0, stream>>>(x, ln1g, ln1b, wqkv, ln_buf, wt_qkv);

  // QKV: R13 config (1D grid)
  gemm_kernel<0, 128, 64, 6><<<dim3((CQKV / 64) * 64), blk, 0, stream>>>(
      ln_buf, wt_qkv, CMOD, nullptr, nullptr, q_buf, k_buf, vt_buf);

  // attn: grid 2304 x 128 threads (2 waves x 32 q-rows), XCD swizzle (bh = n & 15)
  attn_kernel<<<dim3(2304), dim3(128), 0, stream>>>(q_buf, k_buf, vt_buf, po, pl);

  // reduce (512 blocks) + wproj/wff1/wff2 transposes (2304 blocks)
  reduce_kernel<<<dim3(2816), blk, 0, stream>>>(po, pl, attn,
                                                wproj, wff1, wff2,
                                                wt_proj, wt_ff1, wt_ff2);

  // proj: R13 config (1D grid)
  gemm_kernel<1, 128, 64, 4><<<dim3((CMOD / 64) * 64), blk, 0, stream>>>(
      attn, wt_proj, CMOD, x, x2, nullptr, nullptr, nullptr);

  ln_kernel<<<dim3(BT / 4), blk, 0, stream>>>(x2, ln2g, ln2b, ln_buf);

  // FF1: R13 config (1D grid, KS reverted to 1-equivalent)
  gemm_kernel<2, 128, 64, 6><<<dim3((DFF / 64) * 64), blk, 0, stream>>>(
      ln_buf, wt_ff1, CMOD, nullptr, nullptr, h1, nullptr, nullptr);

  // FF2: R13 config (1D grid)
  gemm_kernel<3, 128, 64, 4><<<dim3((CMOD / 64) * 64), blk, 0, stream>>>(
      h1, wt_ff2, DFF, x2, out, nullptr, nullptr, nullptr);
}